// Round 6
// baseline (507.714 us; speedup 1.0000x reference)
//
#include <hip/hip_runtime.h>
#include <hip/hip_bf16.h>

// ---------------------------------------------------------------------------
// FocusPolicy pipeline, MI355X.
//  K0  k_cvtall: conv1_w+stem_w -> bf16, x -> padded bf16 rows, zero partial
//  K1 stem conv 7x7/s2 MFMA bf16 + in-register BN partials -> stem, partial
//     one-wave blocks, private slab, zero barriers. BN tail: m-group shuffle
//     reduce -> 512B LDS park (disjoint from T) -> 2 wave atomicAdd insts
//     into 8-replica partial[8][128].
//  K3 BN finalize inline (sums 8 replicas) + relu + maxpool3/2p1 -> f
//  K4 grid_sample both rotations, ZERO-GUARD-RING band
//  K5 roialign: one block per (n,c,job), RoI region staged in LDS
//  K6 conv1 3x3 (704->64) MFMA bf16, split-K=9 (2448 blocks), dbuf -> c1p
//     (c1p aliases f region — f dead after roialign)
//  K6b reduce split-K(9) + bias                       -> c1  (16,64,21,21)
//  K7 BN1 stats;  K8 BN+relu+maxpool2/2;  K9 conv2 (LDS);  K10 fc1;  K11 head
// ---------------------------------------------------------------------------

#define C5 0.9961946980917455f
#define S5 0.08715574274765817f

typedef __attribute__((ext_vector_type(8))) short short8;
typedef __attribute__((ext_vector_type(4))) float f32x4;

typedef __attribute__((address_space(3))) ushort lds_ushort;
typedef const __attribute__((address_space(1))) ushort gbl_ushort;

__device__ __forceinline__ ushort f2bf_bits(float v) {
    __hip_bfloat16 b = __float2bfloat16(v);
    ushort u;
    __builtin_memcpy(&u, &b, 2);
    return u;
}
__device__ __forceinline__ float bfbits2f(ushort u) {
    __hip_bfloat16 b;
    __builtin_memcpy(&b, &u, 2);
    return __bfloat162float(b);
}

// ==== K0: fused convert: x rows (blocks < 12627), weights + zero partial ====
__global__ __launch_bounds__(256) void k_cvtall(const float* __restrict__ x,
                                                ushort* __restrict__ xbf,
                                                const float* __restrict__ w1,
                                                __hip_bfloat16* __restrict__ w1b,
                                                const float* __restrict__ sw,
                                                __hip_bfloat16* __restrict__ w2b,
                                                float* __restrict__ partial) {
    const int bx = blockIdx.x;
    if (bx < 12627) {
        const int t = bx * 256 + threadIdx.x;       // 16*518*390 = 3232480
        if (t >= 3232480) return;
        const int n = t / 202020;
        const int r = t - n * 202020;
        const int row = r / 390, col = r - row * 390;
        const int ih = row - 3;
        float4 v = {0.f, 0.f, 0.f, 0.f};
        if ((unsigned)ih < 512u && col >= 3 && col <= 386)
            v = *(const float4*)(x + (size_t)n * 786432 + (size_t)ih * 1536 + 4 * col - 12);
        uint2 p;
        p.x = (uint)f2bf_bits(v.x) | ((uint)f2bf_bits(v.y) << 16);
        p.y = (uint)f2bf_bits(v.z) | ((uint)f2bf_bits(v.w) << 16);
        *(uint2*)(xbf + 4 * (size_t)t) = p;
    } else {
        const int t = (bx - 12627) * 256 + threadIdx.x;  // 418816 used
        if (t < 405504) {
            w1b[t] = __float2bfloat16(w1[t]);
        } else if (t < 417792) {
            const int e = t - 405504;
            const int oc = e / 192, k = e - oc * 192;
            const int kh = k / 24, u = k - kh * 24;
            float v = 0.f;
            if (u >= 3 && kh < 7) {
                int tt = u - 3;
                int kw = tt / 3, ci = tt - kw * 3;
                v = sw[oc * 147 + ci * 49 + kh * 7 + kw];
            }
            w2b[e] = __float2bfloat16(v);
        } else if (t < 418816) {
            partial[t - 417792] = 0.f;   // 8 replicas x 128
        }
    }
}

// =================== K1: stem conv MFMA (one wave / block) =================
// 16384 one-wave blocks. XCD swizzle: gi = (bx&7)*2048 + bx>>3; wq = gi&3,
// oh = (gi>>2)&255, n = gi>>10. LDS: slab 8x416 u / T 64x72 u (aliased) +
// sred 64 float2 at u-offset 4608 (disjoint). No __syncthreads anywhere.
__global__ __launch_bounds__(64, 4) void k_stem(const ushort* __restrict__ xbf,
                                                const ushort* __restrict__ w2b,
                                                __hip_bfloat16* __restrict__ out,
                                                float* __restrict__ partial) {
    __shared__ __align__(16) ushort lds[4864];    // slab/T alias + sred tail
    const int bx = blockIdx.x;
    const int gi = ((bx & 7) << 11) + (bx >> 3);
    const int wq = gi & 3;
    const int oh = (gi >> 2) & 255;
    const int n  = gi >> 10;
    const int lane = threadIdx.x;
    const int quad = lane >> 4, m = lane & 15;
    const int p0 = wq * 64;
    float2* sred = (float2*)(lds + 4608);          // 512 B, disjoint from T

    // ---- slab load: 8 rows x 204 dwords, private to this wave ----
    {
        const ushort* src = xbf + (size_t)n * 808080 + (size_t)(oh * 2) * 1560 + 6 * p0;
        if (lane < 51) {
#pragma unroll
            for (int row = 0; row < 8; row++)
                __builtin_amdgcn_global_load_lds((gbl_ushort*)(src + row * 1560 + lane * 8),
                                                 (lds_ushort*)(lds + row * 416 + lane * 8),
                                                 16, 0, 0);
        }
    }
    asm volatile("s_waitcnt vmcnt(0)" ::: "memory");
    __builtin_amdgcn_sched_barrier(0);

    // ---- K-loop: B-frags from private slab (sliding-window im2col) ----
    f32x4 acc[4][4] = {};
#pragma unroll
    for (int ks = 0; ks < 6; ks++) {
        const int g   = ks * 4 + quad;
        const int kh  = g / 3;
        const int gi2 = g - kh * 3;
        const uint* rr = (const uint*)lds + kh * 208 + 4 * gi2;
        short8 b[4];
#pragma unroll
        for (int nt = 0; nt < 4; nt++) {
            const uint* q = rr + 3 * (nt * 16 + m);
            uint4 t = (uint4){q[0], q[1], q[2], q[3]};
            __builtin_memcpy(&b[nt], &t, 16);
        }
        const int ko = ks * 32 + quad * 8;
#pragma unroll
        for (int mt = 0; mt < 4; mt++) {
            const short8 a = *(const short8*)(w2b + (size_t)(mt * 16 + m) * 192 + ko);
#pragma unroll
            for (int nt = 0; nt < 4; nt++)
                acc[mt][nt] = __builtin_amdgcn_mfma_f32_16x16x32_bf16(a, b[nt], acc[mt][nt], 0, 0, 0);
        }
    }

    // ---- BN partials: m-group reduce, park in sred (no barrier needed) ----
#pragma unroll
    for (int mt = 0; mt < 4; mt++) {
#pragma unroll
        for (int r = 0; r < 4; r++) {
            float s = acc[mt][0][r] + acc[mt][1][r] + acc[mt][2][r] + acc[mt][3][r];
            float q = acc[mt][0][r] * acc[mt][0][r] + acc[mt][1][r] * acc[mt][1][r]
                    + acc[mt][2][r] * acc[mt][2][r] + acc[mt][3][r] * acc[mt][3][r];
#pragma unroll
            for (int off = 1; off < 16; off <<= 1) {
                s += __shfl_xor(s, off, 64);
                q += __shfl_xor(q, off, 64);
            }
            if (m == 0)
                sred[mt * 16 + quad * 4 + r] = (float2){s, q};
        }
    }

    // ---- wave-internal transpose (no barrier: same-wave DS is in-order) ----
#pragma unroll
    for (int mt = 0; mt < 4; mt++)
#pragma unroll
        for (int nt = 0; nt < 4; nt++)
#pragma unroll
            for (int r = 0; r < 4; r++)
                lds[(mt * 16 + quad * 4 + r) * 72 + nt * 16 + m] = f2bf_bits(acc[mt][nt][r]);

    // ---- coalesced stores: 8 passes x (8 oc x 128 B) ----
    ushort* outb = (ushort*)out + (size_t)n * 64 * 65536 + oh * 256 + p0;
    const int ocl = lane >> 3, ch = lane & 7;
#pragma unroll
    for (int p = 0; p < 8; p++) {
        const int oc = p * 8 + ocl;
        uint4 v = *(const uint4*)&lds[oc * 72 + ch * 8];
        *(uint4*)(outb + (size_t)oc * 65536 + ch * 8) = v;
    }

    // ---- 2 full-wave atomic instructions into 8-replica partial ----
    {
        float2 v = sred[lane];
        float* pb = partial + ((bx & 7) << 7) + lane * 2;
        atomicAdd(pb, v.x);
        atomicAdd(pb + 1, v.y);
    }
}

__global__ __launch_bounds__(256) void k_bn1stats(const float* __restrict__ c1,
                                                  const float* __restrict__ gamma,
                                                  const float* __restrict__ beta,
                                                  float* __restrict__ stats1) {
    const int c = blockIdx.x;
    const int tid = threadIdx.x;
    float s = 0.f, ss = 0.f;
    for (int e = tid; e < 7056; e += 256) {
        int n = e / 441, p = e - n * 441;
        float v = c1[(n * 64 + c) * 441 + p];
        s += v; ss += v * v;
    }
    __shared__ float sh[8], sh2[8];
#pragma unroll
    for (int off = 32; off; off >>= 1) {
        s += __shfl_xor(s, off, 64);
        ss += __shfl_xor(ss, off, 64);
    }
    if ((tid & 63) == 0) { sh[tid >> 6] = s; sh2[tid >> 6] = ss; }
    __syncthreads();
    if (tid == 0) {
        s = sh[0] + sh[1] + sh[2] + sh[3];
        ss = sh2[0] + sh2[1] + sh2[2] + sh2[3];
        const float inv_n = 1.f / 7056.f;
        float mn = s * inv_n;
        float var = ss * inv_n - mn * mn;
        float a = gamma[c] * rsqrtf(var + 1e-5f);
        stats1[c] = a;
        stats1[64 + c] = beta[c] - mn * a;
    }
}

// ===== K3: BN finalize (8 replicas) + relu + maxpool 3x3/s2/p1 =============
__global__ __launch_bounds__(256) void k_bnpool(const __hip_bfloat16* __restrict__ sin_,
                                                const float* __restrict__ partial,
                                                const float* __restrict__ gamma,
                                                const float* __restrict__ beta,
                                                float* __restrict__ f) {
    const int idx = blockIdx.x * 256 + threadIdx.x;
    const int pwg = idx & 15;
    const int ph = (idx >> 4) & 127;
    const int c = (idx >> 11) & 63;
    const int n = idx >> 17;
    const int pw0 = pwg * 8;
    float S = 0.f, Q = 0.f;
#pragma unroll
    for (int rp = 0; rp < 8; rp++) {
        S += partial[rp * 128 + c * 2];
        Q += partial[rp * 128 + c * 2 + 1];
    }
    const float inv_n = 1.f / 1048576.f;
    const float mn = S * inv_n;
    const float var = Q * inv_n - mn * mn;
    const float a = gamma[c] * rsqrtf(var + 1e-5f);
    const float b = beta[c] - mn * a;
    const uint* base = (const uint*)((const ushort*)sin_ + (size_t)(n * 64 + c) * 65536);

    float colmax[17];
#pragma unroll
    for (int k = 0; k < 17; k++) colmax[k] = -1e30f;

    const int r0 = ph * 2 - 1;
#pragma unroll
    for (int dr = 0; dr < 3; dr++) {
        const int r = r0 + dr;
        const bool rv = (unsigned)r < 256u;
        uint d[9];
        const uint* rp = base + r * 128 + pw0 - 1;
#pragma unroll
        for (int j = 0; j < 9; j++)
            d[j] = (rv && (pw0 > 0 || j > 0)) ? rp[j] : 0u;
#pragma unroll
        for (int j = 0; j < 9; j++) {
            float vhi = a * bfbits2f((ushort)(d[j] >> 16)) + b;
            colmax[2 * j] = rv ? fmaxf(colmax[2 * j], vhi) : colmax[2 * j];
            if (j > 0) {
                float vlo = a * bfbits2f((ushort)(d[j] & 0xFFFFu)) + b;
                colmax[2 * j - 1] = rv ? fmaxf(colmax[2 * j - 1], vlo) : colmax[2 * j - 1];
            }
        }
    }
    if (pw0 == 0) colmax[0] = -1e30f;

    float o[8];
#pragma unroll
    for (int i = 0; i < 8; i++)
        o[i] = fmaxf(fmaxf(colmax[2 * i], fmaxf(colmax[2 * i + 1], colmax[2 * i + 2])), 0.f);
    float* fp = f + (size_t)(n * 64 + c) * 16384 + ph * 128 + pw0;
    *(float4*)fp       = (float4){o[0], o[1], o[2], o[3]};
    *(float4*)(fp + 4) = (float4){o[4], o[5], o[6], o[7]};
}

// ====== K4: grid_sample, both rotations, ZERO-GUARD-RING band ==============
__device__ __forceinline__ float gs_pad(const float* band, int ry0g,
                                        float ix, float iy) {
    float x0f = floorf(ix), y0f = floorf(iy);
    float lx = ix - x0f, ly = iy - y0f;
    float hx = 1.f - lx, hy = 1.f - ly;
    const int base = ((int)y0f - ry0g) * 144 + (int)x0f + 8;
    return band[base] * (hx * hy) + band[base + 144] * (hx * ly)
         + band[base + 1] * (lx * hy) + band[base + 145] * (lx * ly);
}

__global__ __launch_bounds__(256, 3) void k_gridsample2(const float* __restrict__ f,
                                                        float* __restrict__ xt1,
                                                        float* __restrict__ xt2) {
    __shared__ float band[78 * 144];
    const int bx = blockIdx.x;
    const int half = bx & 1;
    const int img_i = bx >> 1;          // n*64+c
    const int h0 = half * 64;
    const int ry0g = half ? 57 : -7;
    const float* img = f + (size_t)img_i * 16384;
    const int tid = threadIdx.x;
    for (int e = tid; e < 78 * 36; e += 256) {
        const int r = e / 36, q = e - r * 36;
        const int gr = ry0g + r;
        float4 v = {0.f, 0.f, 0.f, 0.f};
        if ((unsigned)gr < 128u && q >= 2 && q <= 33)
            v = *(const float4*)(img + gr * 128 + 4 * q - 8);
        ((float4*)band)[e] = v;
    }
    __syncthreads();

    float* o1 = xt1 + (size_t)img_i * 16384 + h0 * 128;
    float* o2 = xt2 + (size_t)img_i * 16384 + h0 * 128;
    for (int e = tid; e < 8192; e += 256) {
        const int h = h0 + (e >> 7);
        const int w = e & 127;
        float gx = (2 * w + 1) * (1.f / 128.f) - 1.f;
        float gy = (2 * h + 1) * (1.f / 128.f) - 1.f;
        float g0a = C5 * gx + S5 * gy,  g1a = -S5 * gx + C5 * gy;
        float g0b = C5 * gx - S5 * gy,  g1b =  S5 * gx + C5 * gy;
        o1[e] = gs_pad(band, ry0g, ((g0a + 1.f) * 128.f - 1.f) * 0.5f,
                                   ((g1a + 1.f) * 128.f - 1.f) * 0.5f);
        o2[e] = gs_pad(band, ry0g, ((g0b + 1.f) * 128.f - 1.f) * 0.5f,
                                   ((g1b + 1.f) * 128.f - 1.f) * 0.5f);
    }
}

// ========= K5: roialign, LDS-staged RoI region, one block per (n,c,job) ====
__global__ __launch_bounds__(256) void k_roialign(const float* __restrict__ f,
                                                  const float* __restrict__ xt1,
                                                  const float* __restrict__ xt2,
                                                  const float* __restrict__ box,
                                                  __hip_bfloat16* __restrict__ h) {
    __shared__ float reg[52 * 53];
    const int bx = blockIdx.x;          // 16n * 64c * 11job = 11264
    const int job = bx % 11;
    const int nc = bx / 11;
    const int c = nc & 63;
    const int n = nc >> 6;
    int j, cbase;
    const float* src;
    if (job < 7)      { j = job;     cbase = job * 64;             src = f;   }
    else if (job < 9) { j = job - 7; cbase = 448 + (job - 7) * 64; src = xt1; }
    else              { j = job - 9; cbase = 576 + (job - 9) * 64; src = xt2; }
    const float* bp = box + n * 28 + j * 4;
    const float x1 = bp[0] * 0.25f, y1 = bp[1] * 0.25f;
    const float x2 = bp[2] * 0.25f, y2 = bp[3] * 0.25f;
    const float bw = fmaxf(x2 - x1, 1.f) * (1.f / 23.f);
    const float bh = fmaxf(y2 - y1, 1.f) * (1.f / 23.f);

    const int ry0 = (int)floorf(fminf(fmaxf(y1 + 0.25f * bh, 0.f), 127.f));
    int ry1 = min((int)floorf(fminf(fmaxf(y1 + 22.75f * bh, 0.f), 127.f)) + 1, 127);
    ry1 = min(ry1, ry0 + 51);
    const int rx0 = (int)floorf(fminf(fmaxf(x1 + 0.25f * bw, 0.f), 127.f));
    int rx1 = min((int)floorf(fminf(fmaxf(x1 + 22.75f * bw, 0.f), 127.f)) + 1, 127);
    rx1 = min(rx1, rx0 + 51);
    const int RH = ry1 - ry0 + 1, RW = rx1 - rx0 + 1;

    const float* img = src + (size_t)(n * 64 + c) * 16384;
    const int tid = threadIdx.x;
    const int lane = tid & 63, wv = tid >> 6;
    for (int r = wv; r < RH; r += 4)
        if (lane < RW)
            reg[r * 53 + lane] = img[(ry0 + r) * 128 + rx0 + lane];
    __syncthreads();

    __hip_bfloat16* hb = h + (size_t)(n * 704 + cbase + c) * 529;
    for (int pp = tid; pp < 529; pp += 256) {
        const int ph = pp / 23, pw = pp - ph * 23;
        float sum = 0.f;
#pragma unroll
        for (int s = 0; s < 4; s++) {
            const int r1 = s >> 1, r2 = s & 1;
            const float yv = y1 + (ph + r1 * 0.5f + 0.25f) * bh;
            const float xv = x1 + (pw + r2 * 0.5f + 0.25f) * bw;
            const bool ok = !(yv < -1.f || yv > 128.f || xv < -1.f || xv > 128.f);
            float y = fminf(fmaxf(yv, 0.f), 127.f);
            float x = fminf(fmaxf(xv, 0.f), 127.f);
            float y0f = floorf(y), x0f = floorf(x);
            int y0 = (int)y0f, x0 = (int)x0f;
            int iy0 = y0 - ry0, ix0 = x0 - rx0;
            int iy1 = min(y0 + 1, 127) - ry0, ix1 = min(x0 + 1, 127) - rx0;
            float ly = y - y0f, lx = x - x0f;
            float hy = 1.f - ly, hx = 1.f - lx;
            const float sc = ok ? 1.f : 0.f;
            sum += sc * (reg[iy0 * 53 + ix0] * (hy * hx) + reg[iy0 * 53 + ix1] * (hy * lx)
                       + reg[iy1 * 53 + ix0] * (ly * hx) + reg[iy1 * 53 + ix1] * (ly * lx));
        }
        hb[pp] = __float2bfloat16(sum * 0.25f);
    }
}

// ========= K6: conv1 MFMA bf16, split-K=9, double-buffered staging =========
// 2448 blocks (17 pos-tiles x 16 n x 9 K-splits), 704 K-elems (11 iters) each.
__global__ __launch_bounds__(256) void k_conv1m(const ushort* __restrict__ hb,
                                                const ushort* __restrict__ w1b,
                                                float* __restrict__ c1p) {
    __shared__ __align__(16) ushort Bs[2][2][32][40];  // [buf][panel][pos][kk]
    const int bx = blockIdx.x;
    const int pt = bx % 17;
    const int n  = (bx / 17) & 15;
    const int s  = bx / 272;
    const int tid = threadIdx.x;
    const int w = tid >> 6, lane = tid & 63;
    const int quad = lane >> 4, m = lane & 15;
    const int kbase = s * 704;
    const int posb = pt * 32;
    const size_t hb_n = (size_t)n * 704 * 529;
    f32x4 acc0 = {0.f, 0.f, 0.f, 0.f};
    f32x4 acc1 = {0.f, 0.f, 0.f, 0.f};
    const ushort* wrow = w1b + (size_t)(w * 16 + m) * 6336;

    int ep[8], ek[8], epos[8];
#pragma unroll
    for (int i = 0; i < 8; i++) {
        const int e = tid + 256 * i;
        ep[i] = e >> 10; ek[i] = (e >> 5) & 31; epos[i] = e & 31;
    }
    ushort rbuf[8];
#pragma unroll
    for (int i = 0; i < 8; i++) {          // preload it=0
        const int k = kbase + ep[i] * 32 + ek[i];
        const int ci = k / 9, tap = k - ci * 9;
        const int kh = tap / 3, kw = tap - kh * 3;
        rbuf[i] = hb[hb_n + (size_t)ci * 529 + kh * 23 + kw + posb + epos[i]];
    }
#pragma unroll
    for (int i = 0; i < 8; i++) Bs[0][ep[i]][epos[i]][ek[i]] = rbuf[i];

    for (int it = 0; it < 11; it++) {
        __syncthreads();                    // Bs[it&1] ready
        const int cur = it & 1;
        if (it < 10) {
            const int k0 = kbase + (it + 1) * 64;
#pragma unroll
            for (int i = 0; i < 8; i++) {
                const int k = k0 + ep[i] * 32 + ek[i];
                const int ci = k / 9, tap = k - ci * 9;
                const int kh = tap / 3, kw = tap - kh * 3;
                rbuf[i] = hb[hb_n + (size_t)ci * 529 + kh * 23 + kw + posb + epos[i]];
            }
        }
        const int k0 = kbase + it * 64;
        const short8 a0  = *(const short8*)(wrow + k0 + quad * 8);
        const short8 a1  = *(const short8*)(wrow + k0 + 32 + quad * 8);
        const short8 b00 = *(const short8*)&Bs[cur][0][m][quad * 8];
        const short8 b01 = *(const short8*)&Bs[cur][0][16 + m][quad * 8];
        const short8 b10 = *(const short8*)&Bs[cur][1][m][quad * 8];
        const short8 b11 = *(const short8*)&Bs[cur][1][16 + m][quad * 8];
        acc0 = __builtin_amdgcn_mfma_f32_16x16x32_bf16(a0, b00, acc0, 0, 0, 0);
        acc1 = __builtin_amdgcn_mfma_f32_16x16x32_bf16(a0, b01, acc1, 0, 0, 0);
        acc0 = __builtin_amdgcn_mfma_f32_16x16x32_bf16(a1, b10, acc0, 0, 0, 0);
        acc1 = __builtin_amdgcn_mfma_f32_16x16x32_bf16(a1, b11, acc1, 0, 0, 0);
        if (it < 10) {
#pragma unroll
            for (int i = 0; i < 8; i++) Bs[cur ^ 1][ep[i]][epos[i]][ek[i]] = rbuf[i];
        }
    }
    float* outp = c1p + ((size_t)(s * 16 + n) * 64) * 544;
#pragma unroll
    for (int r = 0; r < 4; r++) {
        const int oc = w * 16 + quad * 4 + r;
        outp[(size_t)oc * 544 + posb + m]      = acc0[r];
        outp[(size_t)oc * 544 + posb + 16 + m] = acc1[r];
    }
}

// =================== K6b: split-K(9) reduce + bias =========================
__global__ __launch_bounds__(256) void k_c1red(const float* __restrict__ c1p,
                                               const float* __restrict__ b1,
                                               float* __restrict__ c1) {
    const int t = blockIdx.x * 256 + threadIdx.x;   // 451584 exact
    const int p = t % 441;
    const int oc = (t / 441) % 64;
    const int n = t / 28224;
    const int ph = p / 21, pw = p - ph * 21;
    const int p529 = ph * 23 + pw;
    const size_t base = ((size_t)n * 64 + oc) * 544 + p529;
    const size_t sstr = (size_t)16 * 64 * 544;
    float v = 0.f;
#pragma unroll
    for (int k = 0; k < 9; k++) v += c1p[base + k * sstr];
    c1[t] = v + b1[oc];
}

// ================ K8: BN1 apply + relu + maxpool 2x2/s2 ====================
__global__ __launch_bounds__(256) void k_bnpool2(const float* __restrict__ c1,
                                                 const float* __restrict__ stats1,
                                                 float* __restrict__ p1) {
    const int t = blockIdx.x * 256 + threadIdx.x;   // 102400 exact
    const int pw = t % 10;
    const int ph = (t / 10) % 10;
    const int c = (t / 100) % 64;
    const int n = t / 6400;
    const float a = stats1[c], b = stats1[64 + c];
    const float* base = c1 + (size_t)(n * 64 + c) * 441;
    const int r = ph * 2, cc = pw * 2;
    float v0 = a * base[r * 21 + cc] + b;
    float v1 = a * base[r * 21 + cc + 1] + b;
    float v2 = a * base[(r + 1) * 21 + cc] + b;
    float v3 = a * base[(r + 1) * 21 + cc + 1] + b;
    p1[t] = fmaxf(fmaxf(fmaxf(v0, v1), fmaxf(v2, v3)), 0.f);
}

// ========== K9: conv2 3x3 (64->32) + bias + relu, LDS-staged ===============
__global__ __launch_bounds__(256) void k_conv2(const float* __restrict__ p1,
                                               const float* __restrict__ w2,
                                               const float* __restrict__ b2,
                                               float* __restrict__ c2) {
    __shared__ float ip[6400];      // 64 ci x 100
    __shared__ float wl[2304];      // 4 oc x 576
    const int bx = blockIdx.x;
    const int n = bx >> 3, ocq = bx & 7;
    const int tid = threadIdx.x;
    const float4* p14 = (const float4*)(p1 + (size_t)n * 6400);
    float4* ip4 = (float4*)ip;
    for (int e = tid; e < 1600; e += 256) ip4[e] = p14[e];
    for (int e = tid; e < 2304; e += 256) wl[e] = w2[ocq * 2304 + e];
    __syncthreads();

    const int ocl = tid >> 6, pos = tid & 63;
    const int ph = pos >> 3, pw = pos & 7;
    const int oc = ocq * 4 + ocl;
    float s = b2[oc];
    const float* wb = wl + ocl * 576;
    const float* ib = ip + ph * 10 + pw;
    for (int ci = 0; ci < 64; ci++) {
        const float* r = ib + ci * 100;
        const float* ww = wb + ci * 9;
        s += r[0] * ww[0] + r[1] * ww[1] + r[2] * ww[2]
           + r[10] * ww[3] + r[11] * ww[4] + r[12] * ww[5]
           + r[20] * ww[6] + r[21] * ww[7] + r[22] * ww[8];
    }
    c2[(size_t)(n * 32 + oc) * 64 + pos] = fmaxf(s, 0.f);
}

// ======================= K10: fc1 + relu ===================================
__global__ __launch_bounds__(64) void k_fc1(const float* __restrict__ c2,
                                            const float* __restrict__ fw,
                                            const float* __restrict__ fb,
                                            float* __restrict__ fo) {
    const int bx = blockIdx.x;
    const int oc = bx & 127, n = bx >> 7;
    const int lane = threadIdx.x;
    const float* a = c2 + (size_t)n * 2048;
    const float* w = fw + (size_t)oc * 2048;
    float s = 0.f;
    for (int k = lane; k < 2048; k += 64) s += a[k] * w[k];
#pragma unroll
    for (int off = 32; off; off >>= 1) s += __shfl_xor(s, off, 64);
    if (lane == 0) fo[n * 128 + oc] = fmaxf(s + fb[oc], 0.f);
}

// ======================= K11: head + tanh ==================================
__global__ __launch_bounds__(64) void k_head(const float* __restrict__ fo,
                                             const float* __restrict__ hw,
                                             const float* __restrict__ hb,
                                             float* __restrict__ out) {
    const int bx = blockIdx.x;
    const int oc = bx % 12, n = bx / 12;
    const int lane = threadIdx.x;
    float s = 0.f;
    for (int k = lane; k < 128; k += 64) s += fo[n * 128 + k] * hw[oc * 128 + k];
#pragma unroll
    for (int off = 32; off; off >>= 1) s += __shfl_xor(s, off, 64);
    if (lane == 0) out[bx] = tanhf(s + hb[oc]);
}

// ===========================================================================
extern "C" void kernel_launch(void* const* d_in, const int* in_sizes, int n_in,
                              void* d_out, int out_size, void* d_ws, size_t ws_size,
                              hipStream_t stream) {
    const float* x       = (const float*)d_in[0];
    const float* box     = (const float*)d_in[1];
    const float* stem_w  = (const float*)d_in[2];
    const float* stem_g  = (const float*)d_in[3];
    const float* stem_b  = (const float*)d_in[4];
    const float* conv1_w = (const float*)d_in[5];
    const float* conv1_b = (const float*)d_in[6];
    const float* bn1_g   = (const float*)d_in[7];
    const float* bn1_b   = (const float*)d_in[8];
    const float* conv2_w = (const float*)d_in[9];
    const float* conv2_b = (const float*)d_in[10];
    const float* fc1_w   = (const float*)d_in[11];
    const float* fc1_b   = (const float*)d_in[12];
    const float* head_w  = (const float*)d_in[13];
    const float* head_b  = (const float*)d_in[14];
    float* out = (float*)d_out;
    float* w = (float*)d_ws;

    const size_t F_SZ = 16777216;                         // 16*64*128*128
    float* f   = w;                                       // fp32
    ushort* xbf = (ushort*)w;                             // aliases f (dead before k_bnpool)
    float* c1p = w;                                       // aliases f (dead after k_roialign)
                                                          // 9*16*64*544 = 5013504 < F_SZ
    __hip_bfloat16* stem = (__hip_bfloat16*)(w + F_SZ);   // bf16, spans 2*F_SZ floats
    float* xt1 = w + F_SZ;                                // aliases stem (dead after K3)
    float* xt2 = w + 2 * F_SZ;
    float* base3 = w + 3 * F_SZ;
    __hip_bfloat16* hbuf = (__hip_bfloat16*)base3;        // 5958656 els = 2979328+pad
    float* c1   = base3 + 2979392;                        // 451584
    float* p1   = c1 + 451584;                            // 102400
    float* c2   = p1 + 102400;                            // 32768
    float* fo   = c2 + 32768;                             // 2048
    float* partial = fo + 2048;                           // 8 x 128 = 1024
    float* stats1  = partial + 1024;                      // 128
    __hip_bfloat16* w1b = (__hip_bfloat16*)(stats1 + 128); // 405504 els
    __hip_bfloat16* w2b = (__hip_bfloat16*)(stats1 + 128 + 202752); // 12288 els

    k_cvtall<<<14263, 256, 0, stream>>>(x, xbf, conv1_w, w1b, stem_w, w2b, partial);
    k_stem<<<16384, 64, 0, stream>>>(xbf, (const ushort*)w2b, stem, partial);
    k_bnpool<<<8192, 256, 0, stream>>>(stem, partial, stem_g, stem_b, f);
    k_gridsample2<<<2048, 256, 0, stream>>>(f, xt1, xt2);
    k_roialign<<<11264, 256, 0, stream>>>(f, xt1, xt2, box, hbuf);
    k_conv1m<<<2448, 256, 0, stream>>>((const ushort*)hbuf, (const ushort*)w1b, c1p);
    k_c1red<<<1764, 256, 0, stream>>>(c1p, conv1_b, c1);
    k_bn1stats<<<64, 256, 0, stream>>>(c1, bn1_g, bn1_b, stats1);
    k_bnpool2<<<400, 256, 0, stream>>>(c1, stats1, p1);
    k_conv2<<<128, 256, 0, stream>>>(p1, conv2_w, conv2_b, c2);
    k_fc1<<<2048, 64, 0, stream>>>(c2, fc1_w, fc1_b, fo);
    k_head<<<192, 64, 0, stream>>>(fo, head_w, head_b, out);
}

// Round 7
// 416.158 us; speedup vs baseline: 1.2200x; 1.2200x over previous
//
#include <hip/hip_runtime.h>
#include <hip/hip_bf16.h>

// ---------------------------------------------------------------------------
// FocusPolicy pipeline, MI355X.
//  K0  k_cvtall: conv1_w+stem_w -> bf16, x -> padded bf16 rows, zero stats
//  K1 stem conv 7x7/s2 MFMA bf16 (one-wave blocks, zero barriers) -> stem
//     (r5-proven 67us form; BN tail removed — r6's 8-replica atomic fold
//      serialized on 32 cache lines, +111us. Lesson: replicas ~ #waves.)
//  K1b k_sumstem: channel sums of L3-resident stem -> stats_raw (atomics ok:
//      1024 atomics / 128 addrs)
//  K3 BN finalize inline + relu + maxpool3/2p1        -> f   (16,64,128,128)
//  K4 grid_sample both rotations, ZERO-GUARD-RING band
//  K5 roialign: one block per (n,c,job), RoI region staged in LDS
//  K6 conv1 3x3 (704->64) MFMA bf16, split-K=9 (2448 blocks), dbuf -> c1p
//  K6b reduce split-K(9) + bias                       -> c1  (16,64,21,21)
//  K7 BN1 stats;  K8 BN+relu+maxpool2/2;  K9 conv2 (LDS);  K10 fc1;  K11 head
// ---------------------------------------------------------------------------

#define C5 0.9961946980917455f
#define S5 0.08715574274765817f

typedef __attribute__((ext_vector_type(8))) short short8;
typedef __attribute__((ext_vector_type(4))) float f32x4;

typedef __attribute__((address_space(3))) ushort lds_ushort;
typedef const __attribute__((address_space(1))) ushort gbl_ushort;

__device__ __forceinline__ ushort f2bf_bits(float v) {
    __hip_bfloat16 b = __float2bfloat16(v);
    ushort u;
    __builtin_memcpy(&u, &b, 2);
    return u;
}
__device__ __forceinline__ float bfbits2f(ushort u) {
    __hip_bfloat16 b;
    __builtin_memcpy(&b, &u, 2);
    return __bfloat162float(b);
}

// ==== K0: fused convert: x rows (blocks < 12627), weights + zero stats =====
__global__ __launch_bounds__(256) void k_cvtall(const float* __restrict__ x,
                                                ushort* __restrict__ xbf,
                                                const float* __restrict__ w1,
                                                __hip_bfloat16* __restrict__ w1b,
                                                const float* __restrict__ sw,
                                                __hip_bfloat16* __restrict__ w2b,
                                                float* __restrict__ stats_raw) {
    const int bx = blockIdx.x;
    if (bx < 12627) {
        const int t = bx * 256 + threadIdx.x;       // 16*518*390 = 3232480
        if (t >= 3232480) return;
        const int n = t / 202020;
        const int r = t - n * 202020;
        const int row = r / 390, col = r - row * 390;
        const int ih = row - 3;
        float4 v = {0.f, 0.f, 0.f, 0.f};
        if ((unsigned)ih < 512u && col >= 3 && col <= 386)
            v = *(const float4*)(x + (size_t)n * 786432 + (size_t)ih * 1536 + 4 * col - 12);
        uint2 p;
        p.x = (uint)f2bf_bits(v.x) | ((uint)f2bf_bits(v.y) << 16);
        p.y = (uint)f2bf_bits(v.z) | ((uint)f2bf_bits(v.w) << 16);
        *(uint2*)(xbf + 4 * (size_t)t) = p;
    } else {
        const int t = (bx - 12627) * 256 + threadIdx.x;
        if (t < 405504) {
            w1b[t] = __float2bfloat16(w1[t]);
        } else if (t < 417792) {
            const int e = t - 405504;
            const int oc = e / 192, k = e - oc * 192;
            const int kh = k / 24, u = k - kh * 24;
            float v = 0.f;
            if (u >= 3 && kh < 7) {
                int tt = u - 3;
                int kw = tt / 3, ci = tt - kw * 3;
                v = sw[oc * 147 + ci * 49 + kh * 7 + kw];
            }
            w2b[e] = __float2bfloat16(v);
        } else if (t < 417920) {
            stats_raw[t - 417792] = 0.f;     // 128 floats, for k_sumstem
        }
    }
}

// =================== K1: stem conv MFMA (one wave / block) =================
// 16384 one-wave blocks. XCD swizzle: gi = (bx&7)*2048 + bx>>3; wq = gi&3,
// oh = (gi>>2)&255, n = gi>>10. LDS 9216 B: slab 8x416 ushorts aliased by
// 64x72 transpose buffer. No __syncthreads anywhere. (r5 form, 67us.)
__global__ __launch_bounds__(64, 4) void k_stem(const ushort* __restrict__ xbf,
                                                const ushort* __restrict__ w2b,
                                                __hip_bfloat16* __restrict__ out) {
    __shared__ __align__(16) ushort lds[4608];    // T 64x72 aliases slab 8x416
    const int bx = blockIdx.x;
    const int gi = ((bx & 7) << 11) + (bx >> 3);
    const int wq = gi & 3;
    const int oh = (gi >> 2) & 255;
    const int n  = gi >> 10;
    const int lane = threadIdx.x;
    const int quad = lane >> 4, m = lane & 15;
    const int p0 = wq * 64;

    // ---- slab load: 8 rows x 204 dwords, private to this wave ----
    {
        const ushort* src = xbf + (size_t)n * 808080 + (size_t)(oh * 2) * 1560 + 6 * p0;
        if (lane < 51) {
#pragma unroll
            for (int row = 0; row < 8; row++)
                __builtin_amdgcn_global_load_lds((gbl_ushort*)(src + row * 1560 + lane * 8),
                                                 (lds_ushort*)(lds + row * 416 + lane * 8),
                                                 16, 0, 0);
        }
    }
    asm volatile("s_waitcnt vmcnt(0)" ::: "memory");
    __builtin_amdgcn_sched_barrier(0);

    // ---- K-loop: B-frags from private slab (sliding-window im2col) ----
    f32x4 acc[4][4] = {};
#pragma unroll
    for (int ks = 0; ks < 6; ks++) {
        const int g   = ks * 4 + quad;
        const int kh  = g / 3;
        const int gi2 = g - kh * 3;
        const uint* rr = (const uint*)lds + kh * 208 + 4 * gi2;
        short8 b[4];
#pragma unroll
        for (int nt = 0; nt < 4; nt++) {
            const uint* q = rr + 3 * (nt * 16 + m);
            uint4 t = (uint4){q[0], q[1], q[2], q[3]};
            __builtin_memcpy(&b[nt], &t, 16);
        }
        const int ko = ks * 32 + quad * 8;
#pragma unroll
        for (int mt = 0; mt < 4; mt++) {
            const short8 a = *(const short8*)(w2b + (size_t)(mt * 16 + m) * 192 + ko);
#pragma unroll
            for (int nt = 0; nt < 4; nt++)
                acc[mt][nt] = __builtin_amdgcn_mfma_f32_16x16x32_bf16(a, b[nt], acc[mt][nt], 0, 0, 0);
        }
    }

    // ---- wave-internal transpose (no barrier: same-wave DS is in-order) ----
#pragma unroll
    for (int mt = 0; mt < 4; mt++)
#pragma unroll
        for (int nt = 0; nt < 4; nt++)
#pragma unroll
            for (int r = 0; r < 4; r++)
                lds[(mt * 16 + quad * 4 + r) * 72 + nt * 16 + m] = f2bf_bits(acc[mt][nt][r]);

    // ---- coalesced stores: 8 passes x (8 oc x 128 B) ----
    ushort* outb = (ushort*)out + (size_t)n * 64 * 65536 + oh * 256 + p0;
    const int ocl = lane >> 3, ch = lane & 7;
#pragma unroll
    for (int p = 0; p < 8; p++) {
        const int oc = p * 8 + ocl;
        uint4 v = *(const uint4*)&lds[oc * 72 + ch * 8];
        *(uint4*)(outb + (size_t)oc * 65536 + ch * 8) = v;
    }
}

// ========= K1b: channel sums of stem (bf16) -> stats_raw (atomic) ==========
// 512 blocks: c = bx>>3, s = bx&7 (n-pair). 1024 atomics over 128 addrs.
__global__ __launch_bounds__(256) void k_sumstem(const ushort* __restrict__ stem,
                                                 float* __restrict__ stats_raw) {
    const int c = blockIdx.x >> 3, s = blockIdx.x & 7;
    const int tid = threadIdx.x;
    const uint4* b0 = (const uint4*)(stem + ((size_t)(s * 2) * 64 + c) * 65536);
    const uint4* b1 = (const uint4*)(stem + ((size_t)(s * 2 + 1) * 64 + c) * 65536);
    float sum = 0.f, sq = 0.f;
    for (int i = tid; i < 8192; i += 256) {
        uint4 v0 = b0[i], v1 = b1[i];
#pragma unroll
        for (int k = 0; k < 4; k++) {
            uint u0 = ((const uint*)&v0)[k], u1 = ((const uint*)&v1)[k];
            float a0 = __uint_as_float(u0 << 16);
            float a1 = __uint_as_float(u0 & 0xffff0000u);
            float a2 = __uint_as_float(u1 << 16);
            float a3 = __uint_as_float(u1 & 0xffff0000u);
            sum += a0 + a1 + a2 + a3;
            sq = fmaf(a0, a0, fmaf(a1, a1, fmaf(a2, a2, fmaf(a3, a3, sq))));
        }
    }
#pragma unroll
    for (int off = 32; off; off >>= 1) {
        sum += __shfl_xor(sum, off, 64);
        sq  += __shfl_xor(sq, off, 64);
    }
    __shared__ float shS[4], shQ[4];
    if ((tid & 63) == 0) { shS[tid >> 6] = sum; shQ[tid >> 6] = sq; }
    __syncthreads();
    if (tid == 0) {
        atomicAdd(&stats_raw[c * 2],     shS[0] + shS[1] + shS[2] + shS[3]);
        atomicAdd(&stats_raw[c * 2 + 1], shQ[0] + shQ[1] + shQ[2] + shQ[3]);
    }
}

__global__ __launch_bounds__(256) void k_bn1stats(const float* __restrict__ c1,
                                                  const float* __restrict__ gamma,
                                                  const float* __restrict__ beta,
                                                  float* __restrict__ stats1) {
    const int c = blockIdx.x;
    const int tid = threadIdx.x;
    float s = 0.f, ss = 0.f;
    for (int e = tid; e < 7056; e += 256) {
        int n = e / 441, p = e - n * 441;
        float v = c1[(n * 64 + c) * 441 + p];
        s += v; ss += v * v;
    }
    __shared__ float sh[8], sh2[8];
#pragma unroll
    for (int off = 32; off; off >>= 1) {
        s += __shfl_xor(s, off, 64);
        ss += __shfl_xor(ss, off, 64);
    }
    if ((tid & 63) == 0) { sh[tid >> 6] = s; sh2[tid >> 6] = ss; }
    __syncthreads();
    if (tid == 0) {
        s = sh[0] + sh[1] + sh[2] + sh[3];
        ss = sh2[0] + sh2[1] + sh2[2] + sh2[3];
        const float inv_n = 1.f / 7056.f;
        float mn = s * inv_n;
        float var = ss * inv_n - mn * mn;
        float a = gamma[c] * rsqrtf(var + 1e-5f);
        stats1[c] = a;
        stats1[64 + c] = beta[c] - mn * a;
    }
}

// ===== K3: BN finalize inline + relu + maxpool 3x3/s2/p1 ===================
__global__ __launch_bounds__(256) void k_bnpool(const __hip_bfloat16* __restrict__ sin_,
                                                const float* __restrict__ stats_raw,
                                                const float* __restrict__ gamma,
                                                const float* __restrict__ beta,
                                                float* __restrict__ f) {
    const int idx = blockIdx.x * 256 + threadIdx.x;
    const int pwg = idx & 15;
    const int ph = (idx >> 4) & 127;
    const int c = (idx >> 11) & 63;
    const int n = idx >> 17;
    const int pw0 = pwg * 8;
    const float inv_n = 1.f / 1048576.f;
    const float S = stats_raw[c * 2], Q = stats_raw[c * 2 + 1];
    const float mn = S * inv_n;
    const float var = Q * inv_n - mn * mn;
    const float a = gamma[c] * rsqrtf(var + 1e-5f);
    const float b = beta[c] - mn * a;
    const uint* base = (const uint*)((const ushort*)sin_ + (size_t)(n * 64 + c) * 65536);

    float colmax[17];
#pragma unroll
    for (int k = 0; k < 17; k++) colmax[k] = -1e30f;

    const int r0 = ph * 2 - 1;
#pragma unroll
    for (int dr = 0; dr < 3; dr++) {
        const int r = r0 + dr;
        const bool rv = (unsigned)r < 256u;
        uint d[9];
        const uint* rp = base + r * 128 + pw0 - 1;
#pragma unroll
        for (int j = 0; j < 9; j++)
            d[j] = (rv && (pw0 > 0 || j > 0)) ? rp[j] : 0u;
#pragma unroll
        for (int j = 0; j < 9; j++) {
            float vhi = a * bfbits2f((ushort)(d[j] >> 16)) + b;
            colmax[2 * j] = rv ? fmaxf(colmax[2 * j], vhi) : colmax[2 * j];
            if (j > 0) {
                float vlo = a * bfbits2f((ushort)(d[j] & 0xFFFFu)) + b;
                colmax[2 * j - 1] = rv ? fmaxf(colmax[2 * j - 1], vlo) : colmax[2 * j - 1];
            }
        }
    }
    if (pw0 == 0) colmax[0] = -1e30f;

    float o[8];
#pragma unroll
    for (int i = 0; i < 8; i++)
        o[i] = fmaxf(fmaxf(colmax[2 * i], fmaxf(colmax[2 * i + 1], colmax[2 * i + 2])), 0.f);
    float* fp = f + (size_t)(n * 64 + c) * 16384 + ph * 128 + pw0;
    *(float4*)fp       = (float4){o[0], o[1], o[2], o[3]};
    *(float4*)(fp + 4) = (float4){o[4], o[5], o[6], o[7]};
}

// ====== K4: grid_sample, both rotations, ZERO-GUARD-RING band ==============
__device__ __forceinline__ float gs_pad(const float* band, int ry0g,
                                        float ix, float iy) {
    float x0f = floorf(ix), y0f = floorf(iy);
    float lx = ix - x0f, ly = iy - y0f;
    float hx = 1.f - lx, hy = 1.f - ly;
    const int base = ((int)y0f - ry0g) * 144 + (int)x0f + 8;
    return band[base] * (hx * hy) + band[base + 144] * (hx * ly)
         + band[base + 1] * (lx * hy) + band[base + 145] * (lx * ly);
}

__global__ __launch_bounds__(256, 3) void k_gridsample2(const float* __restrict__ f,
                                                        float* __restrict__ xt1,
                                                        float* __restrict__ xt2) {
    __shared__ float band[78 * 144];
    const int bx = blockIdx.x;
    const int half = bx & 1;
    const int img_i = bx >> 1;          // n*64+c
    const int h0 = half * 64;
    const int ry0g = half ? 57 : -7;
    const float* img = f + (size_t)img_i * 16384;
    const int tid = threadIdx.x;
    for (int e = tid; e < 78 * 36; e += 256) {
        const int r = e / 36, q = e - r * 36;
        const int gr = ry0g + r;
        float4 v = {0.f, 0.f, 0.f, 0.f};
        if ((unsigned)gr < 128u && q >= 2 && q <= 33)
            v = *(const float4*)(img + gr * 128 + 4 * q - 8);
        ((float4*)band)[e] = v;
    }
    __syncthreads();

    float* o1 = xt1 + (size_t)img_i * 16384 + h0 * 128;
    float* o2 = xt2 + (size_t)img_i * 16384 + h0 * 128;
    for (int e = tid; e < 8192; e += 256) {
        const int h = h0 + (e >> 7);
        const int w = e & 127;
        float gx = (2 * w + 1) * (1.f / 128.f) - 1.f;
        float gy = (2 * h + 1) * (1.f / 128.f) - 1.f;
        float g0a = C5 * gx + S5 * gy,  g1a = -S5 * gx + C5 * gy;
        float g0b = C5 * gx - S5 * gy,  g1b =  S5 * gx + C5 * gy;
        o1[e] = gs_pad(band, ry0g, ((g0a + 1.f) * 128.f - 1.f) * 0.5f,
                                   ((g1a + 1.f) * 128.f - 1.f) * 0.5f);
        o2[e] = gs_pad(band, ry0g, ((g0b + 1.f) * 128.f - 1.f) * 0.5f,
                                   ((g1b + 1.f) * 128.f - 1.f) * 0.5f);
    }
}

// ========= K5: roialign, LDS-staged RoI region, one block per (n,c,job) ====
__global__ __launch_bounds__(256) void k_roialign(const float* __restrict__ f,
                                                  const float* __restrict__ xt1,
                                                  const float* __restrict__ xt2,
                                                  const float* __restrict__ box,
                                                  __hip_bfloat16* __restrict__ h) {
    __shared__ float reg[52 * 53];
    const int bx = blockIdx.x;          // 16n * 64c * 11job = 11264
    const int job = bx % 11;
    const int nc = bx / 11;
    const int c = nc & 63;
    const int n = nc >> 6;
    int j, cbase;
    const float* src;
    if (job < 7)      { j = job;     cbase = job * 64;             src = f;   }
    else if (job < 9) { j = job - 7; cbase = 448 + (job - 7) * 64; src = xt1; }
    else              { j = job - 9; cbase = 576 + (job - 9) * 64; src = xt2; }
    const float* bp = box + n * 28 + j * 4;
    const float x1 = bp[0] * 0.25f, y1 = bp[1] * 0.25f;
    const float x2 = bp[2] * 0.25f, y2 = bp[3] * 0.25f;
    const float bw = fmaxf(x2 - x1, 1.f) * (1.f / 23.f);
    const float bh = fmaxf(y2 - y1, 1.f) * (1.f / 23.f);

    const int ry0 = (int)floorf(fminf(fmaxf(y1 + 0.25f * bh, 0.f), 127.f));
    int ry1 = min((int)floorf(fminf(fmaxf(y1 + 22.75f * bh, 0.f), 127.f)) + 1, 127);
    ry1 = min(ry1, ry0 + 51);
    const int rx0 = (int)floorf(fminf(fmaxf(x1 + 0.25f * bw, 0.f), 127.f));
    int rx1 = min((int)floorf(fminf(fmaxf(x1 + 22.75f * bw, 0.f), 127.f)) + 1, 127);
    rx1 = min(rx1, rx0 + 51);
    const int RH = ry1 - ry0 + 1, RW = rx1 - rx0 + 1;

    const float* img = src + (size_t)(n * 64 + c) * 16384;
    const int tid = threadIdx.x;
    const int lane = tid & 63, wv = tid >> 6;
    for (int r = wv; r < RH; r += 4)
        if (lane < RW)
            reg[r * 53 + lane] = img[(ry0 + r) * 128 + rx0 + lane];
    __syncthreads();

    __hip_bfloat16* hb = h + (size_t)(n * 704 + cbase + c) * 529;
    for (int pp = tid; pp < 529; pp += 256) {
        const int ph = pp / 23, pw = pp - ph * 23;
        float sum = 0.f;
#pragma unroll
        for (int s = 0; s < 4; s++) {
            const int r1 = s >> 1, r2 = s & 1;
            const float yv = y1 + (ph + r1 * 0.5f + 0.25f) * bh;
            const float xv = x1 + (pw + r2 * 0.5f + 0.25f) * bw;
            const bool ok = !(yv < -1.f || yv > 128.f || xv < -1.f || xv > 128.f);
            float y = fminf(fmaxf(yv, 0.f), 127.f);
            float x = fminf(fmaxf(xv, 0.f), 127.f);
            float y0f = floorf(y), x0f = floorf(x);
            int y0 = (int)y0f, x0 = (int)x0f;
            int iy0 = y0 - ry0, ix0 = x0 - rx0;
            int iy1 = min(y0 + 1, 127) - ry0, ix1 = min(x0 + 1, 127) - rx0;
            float ly = y - y0f, lx = x - x0f;
            float hy = 1.f - ly, hx = 1.f - lx;
            const float sc = ok ? 1.f : 0.f;
            sum += sc * (reg[iy0 * 53 + ix0] * (hy * hx) + reg[iy0 * 53 + ix1] * (hy * lx)
                       + reg[iy1 * 53 + ix0] * (ly * hx) + reg[iy1 * 53 + ix1] * (ly * lx));
        }
        hb[pp] = __float2bfloat16(sum * 0.25f);
    }
}

// ========= K6: conv1 MFMA bf16, split-K=9, double-buffered staging =========
__global__ __launch_bounds__(256) void k_conv1m(const ushort* __restrict__ hb,
                                                const ushort* __restrict__ w1b,
                                                float* __restrict__ c1p) {
    __shared__ __align__(16) ushort Bs[2][2][32][40];  // [buf][panel][pos][kk]
    const int bx = blockIdx.x;
    const int pt = bx % 17;
    const int n  = (bx / 17) & 15;
    const int s  = bx / 272;
    const int tid = threadIdx.x;
    const int w = tid >> 6, lane = tid & 63;
    const int quad = lane >> 4, m = lane & 15;
    const int kbase = s * 704;
    const int posb = pt * 32;
    const size_t hb_n = (size_t)n * 704 * 529;
    f32x4 acc0 = {0.f, 0.f, 0.f, 0.f};
    f32x4 acc1 = {0.f, 0.f, 0.f, 0.f};
    const ushort* wrow = w1b + (size_t)(w * 16 + m) * 6336;

    int ep[8], ek[8], epos[8];
#pragma unroll
    for (int i = 0; i < 8; i++) {
        const int e = tid + 256 * i;
        ep[i] = e >> 10; ek[i] = (e >> 5) & 31; epos[i] = e & 31;
    }
    ushort rbuf[8];
#pragma unroll
    for (int i = 0; i < 8; i++) {          // preload it=0
        const int k = kbase + ep[i] * 32 + ek[i];
        const int ci = k / 9, tap = k - ci * 9;
        const int kh = tap / 3, kw = tap - kh * 3;
        rbuf[i] = hb[hb_n + (size_t)ci * 529 + kh * 23 + kw + posb + epos[i]];
    }
#pragma unroll
    for (int i = 0; i < 8; i++) Bs[0][ep[i]][epos[i]][ek[i]] = rbuf[i];

    for (int it = 0; it < 11; it++) {
        __syncthreads();                    // Bs[it&1] ready
        const int cur = it & 1;
        if (it < 10) {
            const int k0 = kbase + (it + 1) * 64;
#pragma unroll
            for (int i = 0; i < 8; i++) {
                const int k = k0 + ep[i] * 32 + ek[i];
                const int ci = k / 9, tap = k - ci * 9;
                const int kh = tap / 3, kw = tap - kh * 3;
                rbuf[i] = hb[hb_n + (size_t)ci * 529 + kh * 23 + kw + posb + epos[i]];
            }
        }
        const int k0 = kbase + it * 64;
        const short8 a0  = *(const short8*)(wrow + k0 + quad * 8);
        const short8 a1  = *(const short8*)(wrow + k0 + 32 + quad * 8);
        const short8 b00 = *(const short8*)&Bs[cur][0][m][quad * 8];
        const short8 b01 = *(const short8*)&Bs[cur][0][16 + m][quad * 8];
        const short8 b10 = *(const short8*)&Bs[cur][1][m][quad * 8];
        const short8 b11 = *(const short8*)&Bs[cur][1][16 + m][quad * 8];
        acc0 = __builtin_amdgcn_mfma_f32_16x16x32_bf16(a0, b00, acc0, 0, 0, 0);
        acc1 = __builtin_amdgcn_mfma_f32_16x16x32_bf16(a0, b01, acc1, 0, 0, 0);
        acc0 = __builtin_amdgcn_mfma_f32_16x16x32_bf16(a1, b10, acc0, 0, 0, 0);
        acc1 = __builtin_amdgcn_mfma_f32_16x16x32_bf16(a1, b11, acc1, 0, 0, 0);
        if (it < 10) {
#pragma unroll
            for (int i = 0; i < 8; i++) Bs[cur ^ 1][ep[i]][epos[i]][ek[i]] = rbuf[i];
        }
    }
    float* outp = c1p + ((size_t)(s * 16 + n) * 64) * 544;
#pragma unroll
    for (int r = 0; r < 4; r++) {
        const int oc = w * 16 + quad * 4 + r;
        outp[(size_t)oc * 544 + posb + m]      = acc0[r];
        outp[(size_t)oc * 544 + posb + 16 + m] = acc1[r];
    }
}

// =================== K6b: split-K(9) reduce + bias =========================
__global__ __launch_bounds__(256) void k_c1red(const float* __restrict__ c1p,
                                               const float* __restrict__ b1,
                                               float* __restrict__ c1) {
    const int t = blockIdx.x * 256 + threadIdx.x;   // 451584 exact
    const int p = t % 441;
    const int oc = (t / 441) % 64;
    const int n = t / 28224;
    const int ph = p / 21, pw = p - ph * 21;
    const int p529 = ph * 23 + pw;
    const size_t base = ((size_t)n * 64 + oc) * 544 + p529;
    const size_t sstr = (size_t)16 * 64 * 544;
    float v = 0.f;
#pragma unroll
    for (int k = 0; k < 9; k++) v += c1p[base + k * sstr];
    c1[t] = v + b1[oc];
}

// ================ K8: BN1 apply + relu + maxpool 2x2/s2 ====================
__global__ __launch_bounds__(256) void k_bnpool2(const float* __restrict__ c1,
                                                 const float* __restrict__ stats1,
                                                 float* __restrict__ p1) {
    const int t = blockIdx.x * 256 + threadIdx.x;   // 102400 exact
    const int pw = t % 10;
    const int ph = (t / 10) % 10;
    const int c = (t / 100) % 64;
    const int n = t / 6400;
    const float a = stats1[c], b = stats1[64 + c];
    const float* base = c1 + (size_t)(n * 64 + c) * 441;
    const int r = ph * 2, cc = pw * 2;
    float v0 = a * base[r * 21 + cc] + b;
    float v1 = a * base[r * 21 + cc + 1] + b;
    float v2 = a * base[(r + 1) * 21 + cc] + b;
    float v3 = a * base[(r + 1) * 21 + cc + 1] + b;
    p1[t] = fmaxf(fmaxf(fmaxf(v0, v1), fmaxf(v2, v3)), 0.f);
}

// ========== K9: conv2 3x3 (64->32) + bias + relu, LDS-staged ===============
__global__ __launch_bounds__(256) void k_conv2(const float* __restrict__ p1,
                                               const float* __restrict__ w2,
                                               const float* __restrict__ b2,
                                               float* __restrict__ c2) {
    __shared__ float ip[6400];      // 64 ci x 100
    __shared__ float wl[2304];      // 4 oc x 576
    const int bx = blockIdx.x;
    const int n = bx >> 3, ocq = bx & 7;
    const int tid = threadIdx.x;
    const float4* p14 = (const float4*)(p1 + (size_t)n * 6400);
    float4* ip4 = (float4*)ip;
    for (int e = tid; e < 1600; e += 256) ip4[e] = p14[e];
    for (int e = tid; e < 2304; e += 256) wl[e] = w2[ocq * 2304 + e];
    __syncthreads();

    const int ocl = tid >> 6, pos = tid & 63;
    const int ph = pos >> 3, pw = pos & 7;
    const int oc = ocq * 4 + ocl;
    float s = b2[oc];
    const float* wb = wl + ocl * 576;
    const float* ib = ip + ph * 10 + pw;
    for (int ci = 0; ci < 64; ci++) {
        const float* r = ib + ci * 100;
        const float* ww = wb + ci * 9;
        s += r[0] * ww[0] + r[1] * ww[1] + r[2] * ww[2]
           + r[10] * ww[3] + r[11] * ww[4] + r[12] * ww[5]
           + r[20] * ww[6] + r[21] * ww[7] + r[22] * ww[8];
    }
    c2[(size_t)(n * 32 + oc) * 64 + pos] = fmaxf(s, 0.f);
}

// ======================= K10: fc1 + relu ===================================
__global__ __launch_bounds__(64) void k_fc1(const float* __restrict__ c2,
                                            const float* __restrict__ fw,
                                            const float* __restrict__ fb,
                                            float* __restrict__ fo) {
    const int bx = blockIdx.x;
    const int oc = bx & 127, n = bx >> 7;
    const int lane = threadIdx.x;
    const float* a = c2 + (size_t)n * 2048;
    const float* w = fw + (size_t)oc * 2048;
    float s = 0.f;
    for (int k = lane; k < 2048; k += 64) s += a[k] * w[k];
#pragma unroll
    for (int off = 32; off; off >>= 1) s += __shfl_xor(s, off, 64);
    if (lane == 0) fo[n * 128 + oc] = fmaxf(s + fb[oc], 0.f);
}

// ======================= K11: head + tanh ==================================
__global__ __launch_bounds__(64) void k_head(const float* __restrict__ fo,
                                             const float* __restrict__ hw,
                                             const float* __restrict__ hb,
                                             float* __restrict__ out) {
    const int bx = blockIdx.x;
    const int oc = bx % 12, n = bx / 12;
    const int lane = threadIdx.x;
    float s = 0.f;
    for (int k = lane; k < 128; k += 64) s += fo[n * 128 + k] * hw[oc * 128 + k];
#pragma unroll
    for (int off = 32; off; off >>= 1) s += __shfl_xor(s, off, 64);
    if (lane == 0) out[bx] = tanhf(s + hb[oc]);
}

// ===========================================================================
extern "C" void kernel_launch(void* const* d_in, const int* in_sizes, int n_in,
                              void* d_out, int out_size, void* d_ws, size_t ws_size,
                              hipStream_t stream) {
    const float* x       = (const float*)d_in[0];
    const float* box     = (const float*)d_in[1];
    const float* stem_w  = (const float*)d_in[2];
    const float* stem_g  = (const float*)d_in[3];
    const float* stem_b  = (const float*)d_in[4];
    const float* conv1_w = (const float*)d_in[5];
    const float* conv1_b = (const float*)d_in[6];
    const float* bn1_g   = (const float*)d_in[7];
    const float* bn1_b   = (const float*)d_in[8];
    const float* conv2_w = (const float*)d_in[9];
    const float* conv2_b = (const float*)d_in[10];
    const float* fc1_w   = (const float*)d_in[11];
    const float* fc1_b   = (const float*)d_in[12];
    const float* head_w  = (const float*)d_in[13];
    const float* head_b  = (const float*)d_in[14];
    float* out = (float*)d_out;
    float* w = (float*)d_ws;

    const size_t F_SZ = 16777216;                         // 16*64*128*128
    float* f   = w;                                       // fp32
    ushort* xbf = (ushort*)w;                             // aliases f (dead before k_bnpool)
    float* c1p = w;                                       // aliases f (dead after k_roialign)
                                                          // 9*16*64*544 = 5013504 < F_SZ
    __hip_bfloat16* stem = (__hip_bfloat16*)(w + F_SZ);   // bf16, spans 2*F_SZ floats
    float* xt1 = w + F_SZ;                                // aliases stem (dead after K3)
    float* xt2 = w + 2 * F_SZ;
    float* base3 = w + 3 * F_SZ;
    __hip_bfloat16* hbuf = (__hip_bfloat16*)base3;        // 5958656 els = 2979328+pad
    float* c1   = base3 + 2979392;                        // 451584
    float* p1   = c1 + 451584;                            // 102400
    float* c2   = p1 + 102400;                            // 32768
    float* fo   = c2 + 32768;                             // 2048
    float* stats_raw = fo + 2048;                         // 128 (S,Q interleaved)
    float* stats1  = stats_raw + 128;                     // 128
    __hip_bfloat16* w1b = (__hip_bfloat16*)(stats1 + 128); // 405504 els
    __hip_bfloat16* w2b = (__hip_bfloat16*)(stats1 + 128 + 202752); // 12288 els

    k_cvtall<<<14263, 256, 0, stream>>>(x, xbf, conv1_w, w1b, stem_w, w2b, stats_raw);
    k_stem<<<16384, 64, 0, stream>>>(xbf, (const ushort*)w2b, stem);
    k_sumstem<<<512, 256, 0, stream>>>((const ushort*)stem, stats_raw);
    k_bnpool<<<8192, 256, 0, stream>>>(stem, stats_raw, stem_g, stem_b, f);
    k_gridsample2<<<2048, 256, 0, stream>>>(f, xt1, xt2);
    k_roialign<<<11264, 256, 0, stream>>>(f, xt1, xt2, box, hbuf);
    k_conv1m<<<2448, 256, 0, stream>>>((const ushort*)hbuf, (const ushort*)w1b, c1p);
    k_c1red<<<1764, 256, 0, stream>>>(c1p, conv1_b, c1);
    k_bn1stats<<<64, 256, 0, stream>>>(c1, bn1_g, bn1_b, stats1);
    k_bnpool2<<<400, 256, 0, stream>>>(c1, stats1, p1);
    k_conv2<<<128, 256, 0, stream>>>(p1, conv2_w, conv2_b, c2);
    k_fc1<<<2048, 64, 0, stream>>>(c2, fc1_w, fc1_b, fo);
    k_head<<<192, 64, 0, stream>>>(fo, head_w, head_b, out);
}

// Round 8
// 399.495 us; speedup vs baseline: 1.2709x; 1.0417x over previous
//
#include <hip/hip_runtime.h>
#include <hip/hip_bf16.h>

// ---------------------------------------------------------------------------
// FocusPolicy pipeline, MI355X.
//  K0  k_cvtall: conv1_w+stem_w -> bf16, x -> padded bf16 rows, zero stats
//  K1 stem conv 7x7/s2 MFMA bf16 (one-wave blocks, zero barriers) -> stem
//  K1b k_sumstem: channel sums of L3-resident stem -> stats_raw
//  K3 BN finalize inline + relu + maxpool3/2p1        -> f   (16,64,128,128)
//  K5a roialign jobs 0-6 on f (LDS-staged RoI region)
//  K5b roialign jobs 7-10 FUSED with rotation: stage rotated f bbox ->
//      compute needed xt pixels bit-identically to the old gridsample ->
//      tap loop on LDS tile.  (k_gridsample2 deleted: it materialized 134MB
//      of xt but only ~44MB of box regions were ever read.)
//  K6 conv1 3x3 (704->64) MFMA bf16, split-K=9 (2448 blocks), dbuf -> c1p
//  K6b reduce split-K(9) + bias                       -> c1  (16,64,21,21)
//  K7 BN1 stats;  K8 BN+relu+maxpool2/2;  K9 conv2 (LDS);  K10 fc1;  K11 head
// ---------------------------------------------------------------------------

#define C5 0.9961946980917455f
#define S5 0.08715574274765817f

typedef __attribute__((ext_vector_type(8))) short short8;
typedef __attribute__((ext_vector_type(4))) float f32x4;

typedef __attribute__((address_space(3))) ushort lds_ushort;
typedef const __attribute__((address_space(1))) ushort gbl_ushort;

__device__ __forceinline__ ushort f2bf_bits(float v) {
    __hip_bfloat16 b = __float2bfloat16(v);
    ushort u;
    __builtin_memcpy(&u, &b, 2);
    return u;
}
__device__ __forceinline__ float bfbits2f(ushort u) {
    __hip_bfloat16 b;
    __builtin_memcpy(&b, &u, 2);
    return __bfloat162float(b);
}

// ==== K0: fused convert: x rows (blocks < 12627), weights + zero stats =====
__global__ __launch_bounds__(256) void k_cvtall(const float* __restrict__ x,
                                                ushort* __restrict__ xbf,
                                                const float* __restrict__ w1,
                                                __hip_bfloat16* __restrict__ w1b,
                                                const float* __restrict__ sw,
                                                __hip_bfloat16* __restrict__ w2b,
                                                float* __restrict__ stats_raw) {
    const int bx = blockIdx.x;
    if (bx < 12627) {
        const int t = bx * 256 + threadIdx.x;       // 16*518*390 = 3232480
        if (t >= 3232480) return;
        const int n = t / 202020;
        const int r = t - n * 202020;
        const int row = r / 390, col = r - row * 390;
        const int ih = row - 3;
        float4 v = {0.f, 0.f, 0.f, 0.f};
        if ((unsigned)ih < 512u && col >= 3 && col <= 386)
            v = *(const float4*)(x + (size_t)n * 786432 + (size_t)ih * 1536 + 4 * col - 12);
        uint2 p;
        p.x = (uint)f2bf_bits(v.x) | ((uint)f2bf_bits(v.y) << 16);
        p.y = (uint)f2bf_bits(v.z) | ((uint)f2bf_bits(v.w) << 16);
        *(uint2*)(xbf + 4 * (size_t)t) = p;
    } else {
        const int t = (bx - 12627) * 256 + threadIdx.x;
        if (t < 405504) {
            w1b[t] = __float2bfloat16(w1[t]);
        } else if (t < 417792) {
            const int e = t - 405504;
            const int oc = e / 192, k = e - oc * 192;
            const int kh = k / 24, u = k - kh * 24;
            float v = 0.f;
            if (u >= 3 && kh < 7) {
                int tt = u - 3;
                int kw = tt / 3, ci = tt - kw * 3;
                v = sw[oc * 147 + ci * 49 + kh * 7 + kw];
            }
            w2b[e] = __float2bfloat16(v);
        } else if (t < 417920) {
            stats_raw[t - 417792] = 0.f;     // 128 floats, for k_sumstem
        }
    }
}

// =================== K1: stem conv MFMA (one wave / block) =================
// 16384 one-wave blocks. XCD swizzle: gi = (bx&7)*2048 + bx>>3; wq = gi&3,
// oh = (gi>>2)&255, n = gi>>10. LDS 9216 B: slab 8x416 ushorts aliased by
// 64x72 transpose buffer. No __syncthreads anywhere. (r5 form, 67us.)
__global__ __launch_bounds__(64, 4) void k_stem(const ushort* __restrict__ xbf,
                                                const ushort* __restrict__ w2b,
                                                __hip_bfloat16* __restrict__ out) {
    __shared__ __align__(16) ushort lds[4608];    // T 64x72 aliases slab 8x416
    const int bx = blockIdx.x;
    const int gi = ((bx & 7) << 11) + (bx >> 3);
    const int wq = gi & 3;
    const int oh = (gi >> 2) & 255;
    const int n  = gi >> 10;
    const int lane = threadIdx.x;
    const int quad = lane >> 4, m = lane & 15;
    const int p0 = wq * 64;

    // ---- slab load: 8 rows x 204 dwords, private to this wave ----
    {
        const ushort* src = xbf + (size_t)n * 808080 + (size_t)(oh * 2) * 1560 + 6 * p0;
        if (lane < 51) {
#pragma unroll
            for (int row = 0; row < 8; row++)
                __builtin_amdgcn_global_load_lds((gbl_ushort*)(src + row * 1560 + lane * 8),
                                                 (lds_ushort*)(lds + row * 416 + lane * 8),
                                                 16, 0, 0);
        }
    }
    asm volatile("s_waitcnt vmcnt(0)" ::: "memory");
    __builtin_amdgcn_sched_barrier(0);

    // ---- K-loop: B-frags from private slab (sliding-window im2col) ----
    f32x4 acc[4][4] = {};
#pragma unroll
    for (int ks = 0; ks < 6; ks++) {
        const int g   = ks * 4 + quad;
        const int kh  = g / 3;
        const int gi2 = g - kh * 3;
        const uint* rr = (const uint*)lds + kh * 208 + 4 * gi2;
        short8 b[4];
#pragma unroll
        for (int nt = 0; nt < 4; nt++) {
            const uint* q = rr + 3 * (nt * 16 + m);
            uint4 t = (uint4){q[0], q[1], q[2], q[3]};
            __builtin_memcpy(&b[nt], &t, 16);
        }
        const int ko = ks * 32 + quad * 8;
#pragma unroll
        for (int mt = 0; mt < 4; mt++) {
            const short8 a = *(const short8*)(w2b + (size_t)(mt * 16 + m) * 192 + ko);
#pragma unroll
            for (int nt = 0; nt < 4; nt++)
                acc[mt][nt] = __builtin_amdgcn_mfma_f32_16x16x32_bf16(a, b[nt], acc[mt][nt], 0, 0, 0);
        }
    }

    // ---- wave-internal transpose (no barrier: same-wave DS is in-order) ----
#pragma unroll
    for (int mt = 0; mt < 4; mt++)
#pragma unroll
        for (int nt = 0; nt < 4; nt++)
#pragma unroll
            for (int r = 0; r < 4; r++)
                lds[(mt * 16 + quad * 4 + r) * 72 + nt * 16 + m] = f2bf_bits(acc[mt][nt][r]);

    // ---- coalesced stores: 8 passes x (8 oc x 128 B) ----
    ushort* outb = (ushort*)out + (size_t)n * 64 * 65536 + oh * 256 + p0;
    const int ocl = lane >> 3, ch = lane & 7;
#pragma unroll
    for (int p = 0; p < 8; p++) {
        const int oc = p * 8 + ocl;
        uint4 v = *(const uint4*)&lds[oc * 72 + ch * 8];
        *(uint4*)(outb + (size_t)oc * 65536 + ch * 8) = v;
    }
}

// ========= K1b: channel sums of stem (bf16) -> stats_raw (atomic) ==========
__global__ __launch_bounds__(256) void k_sumstem(const ushort* __restrict__ stem,
                                                 float* __restrict__ stats_raw) {
    const int c = blockIdx.x >> 3, s = blockIdx.x & 7;
    const int tid = threadIdx.x;
    const uint4* b0 = (const uint4*)(stem + ((size_t)(s * 2) * 64 + c) * 65536);
    const uint4* b1 = (const uint4*)(stem + ((size_t)(s * 2 + 1) * 64 + c) * 65536);
    float sum = 0.f, sq = 0.f;
    for (int i = tid; i < 8192; i += 256) {
        uint4 v0 = b0[i], v1 = b1[i];
#pragma unroll
        for (int k = 0; k < 4; k++) {
            uint u0 = ((const uint*)&v0)[k], u1 = ((const uint*)&v1)[k];
            float a0 = __uint_as_float(u0 << 16);
            float a1 = __uint_as_float(u0 & 0xffff0000u);
            float a2 = __uint_as_float(u1 << 16);
            float a3 = __uint_as_float(u1 & 0xffff0000u);
            sum += a0 + a1 + a2 + a3;
            sq = fmaf(a0, a0, fmaf(a1, a1, fmaf(a2, a2, fmaf(a3, a3, sq))));
        }
    }
#pragma unroll
    for (int off = 32; off; off >>= 1) {
        sum += __shfl_xor(sum, off, 64);
        sq  += __shfl_xor(sq, off, 64);
    }
    __shared__ float shS[4], shQ[4];
    if ((tid & 63) == 0) { shS[tid >> 6] = sum; shQ[tid >> 6] = sq; }
    __syncthreads();
    if (tid == 0) {
        atomicAdd(&stats_raw[c * 2],     shS[0] + shS[1] + shS[2] + shS[3]);
        atomicAdd(&stats_raw[c * 2 + 1], shQ[0] + shQ[1] + shQ[2] + shQ[3]);
    }
}

__global__ __launch_bounds__(256) void k_bn1stats(const float* __restrict__ c1,
                                                  const float* __restrict__ gamma,
                                                  const float* __restrict__ beta,
                                                  float* __restrict__ stats1) {
    const int c = blockIdx.x;
    const int tid = threadIdx.x;
    float s = 0.f, ss = 0.f;
    for (int e = tid; e < 7056; e += 256) {
        int n = e / 441, p = e - n * 441;
        float v = c1[(n * 64 + c) * 441 + p];
        s += v; ss += v * v;
    }
    __shared__ float sh[8], sh2[8];
#pragma unroll
    for (int off = 32; off; off >>= 1) {
        s += __shfl_xor(s, off, 64);
        ss += __shfl_xor(ss, off, 64);
    }
    if ((tid & 63) == 0) { sh[tid >> 6] = s; sh2[tid >> 6] = ss; }
    __syncthreads();
    if (tid == 0) {
        s = sh[0] + sh[1] + sh[2] + sh[3];
        ss = sh2[0] + sh2[1] + sh2[2] + sh2[3];
        const float inv_n = 1.f / 7056.f;
        float mn = s * inv_n;
        float var = ss * inv_n - mn * mn;
        float a = gamma[c] * rsqrtf(var + 1e-5f);
        stats1[c] = a;
        stats1[64 + c] = beta[c] - mn * a;
    }
}

// ===== K3: BN finalize inline + relu + maxpool 3x3/s2/p1 ===================
__global__ __launch_bounds__(256) void k_bnpool(const __hip_bfloat16* __restrict__ sin_,
                                                const float* __restrict__ stats_raw,
                                                const float* __restrict__ gamma,
                                                const float* __restrict__ beta,
                                                float* __restrict__ f) {
    const int idx = blockIdx.x * 256 + threadIdx.x;
    const int pwg = idx & 15;
    const int ph = (idx >> 4) & 127;
    const int c = (idx >> 11) & 63;
    const int n = idx >> 17;
    const int pw0 = pwg * 8;
    const float inv_n = 1.f / 1048576.f;
    const float S = stats_raw[c * 2], Q = stats_raw[c * 2 + 1];
    const float mn = S * inv_n;
    const float var = Q * inv_n - mn * mn;
    const float a = gamma[c] * rsqrtf(var + 1e-5f);
    const float b = beta[c] - mn * a;
    const uint* base = (const uint*)((const ushort*)sin_ + (size_t)(n * 64 + c) * 65536);

    float colmax[17];
#pragma unroll
    for (int k = 0; k < 17; k++) colmax[k] = -1e30f;

    const int r0 = ph * 2 - 1;
#pragma unroll
    for (int dr = 0; dr < 3; dr++) {
        const int r = r0 + dr;
        const bool rv = (unsigned)r < 256u;
        uint d[9];
        const uint* rp = base + r * 128 + pw0 - 1;
#pragma unroll
        for (int j = 0; j < 9; j++)
            d[j] = (rv && (pw0 > 0 || j > 0)) ? rp[j] : 0u;
#pragma unroll
        for (int j = 0; j < 9; j++) {
            float vhi = a * bfbits2f((ushort)(d[j] >> 16)) + b;
            colmax[2 * j] = rv ? fmaxf(colmax[2 * j], vhi) : colmax[2 * j];
            if (j > 0) {
                float vlo = a * bfbits2f((ushort)(d[j] & 0xFFFFu)) + b;
                colmax[2 * j - 1] = rv ? fmaxf(colmax[2 * j - 1], vlo) : colmax[2 * j - 1];
            }
        }
    }
    if (pw0 == 0) colmax[0] = -1e30f;

    float o[8];
#pragma unroll
    for (int i = 0; i < 8; i++)
        o[i] = fmaxf(fmaxf(colmax[2 * i], fmaxf(colmax[2 * i + 1], colmax[2 * i + 2])), 0.f);
    float* fp = f + (size_t)(n * 64 + c) * 16384 + ph * 128 + pw0;
    *(float4*)fp       = (float4){o[0], o[1], o[2], o[3]};
    *(float4*)(fp + 4) = (float4){o[4], o[5], o[6], o[7]};
}

// ========= K5a: roialign jobs 0-6 on f, LDS-staged RoI region ==============
__global__ __launch_bounds__(256) void k_roialign_f(const float* __restrict__ f,
                                                    const float* __restrict__ box,
                                                    __hip_bfloat16* __restrict__ h) {
    __shared__ float reg[52 * 53];
    const int bx = blockIdx.x;          // 16n * 64c * 7job = 7168
    const int job = bx % 7;
    const int nc = bx / 7;
    const int c = nc & 63;
    const int n = nc >> 6;
    const int j = job, cbase = job * 64;
    const float* bp = box + n * 28 + j * 4;
    const float x1 = bp[0] * 0.25f, y1 = bp[1] * 0.25f;
    const float x2 = bp[2] * 0.25f, y2 = bp[3] * 0.25f;
    const float bw = fmaxf(x2 - x1, 1.f) * (1.f / 23.f);
    const float bh = fmaxf(y2 - y1, 1.f) * (1.f / 23.f);

    const int ry0 = (int)floorf(fminf(fmaxf(y1 + 0.25f * bh, 0.f), 127.f));
    int ry1 = min((int)floorf(fminf(fmaxf(y1 + 22.75f * bh, 0.f), 127.f)) + 1, 127);
    ry1 = min(ry1, ry0 + 51);
    const int rx0 = (int)floorf(fminf(fmaxf(x1 + 0.25f * bw, 0.f), 127.f));
    int rx1 = min((int)floorf(fminf(fmaxf(x1 + 22.75f * bw, 0.f), 127.f)) + 1, 127);
    rx1 = min(rx1, rx0 + 51);
    const int RH = ry1 - ry0 + 1, RW = rx1 - rx0 + 1;

    const float* img = f + (size_t)(n * 64 + c) * 16384;
    const int tid = threadIdx.x;
    const int lane = tid & 63, wv = tid >> 6;
    for (int r = wv; r < RH; r += 4)
        if (lane < RW)
            reg[r * 53 + lane] = img[(ry0 + r) * 128 + rx0 + lane];
    __syncthreads();

    __hip_bfloat16* hb = h + (size_t)(n * 704 + cbase + c) * 529;
    for (int pp = tid; pp < 529; pp += 256) {
        const int ph = pp / 23, pw = pp - ph * 23;
        float sum = 0.f;
#pragma unroll
        for (int s = 0; s < 4; s++) {
            const int r1 = s >> 1, r2 = s & 1;
            const float yv = y1 + (ph + r1 * 0.5f + 0.25f) * bh;
            const float xv = x1 + (pw + r2 * 0.5f + 0.25f) * bw;
            const bool ok = !(yv < -1.f || yv > 128.f || xv < -1.f || xv > 128.f);
            float y = fminf(fmaxf(yv, 0.f), 127.f);
            float x = fminf(fmaxf(xv, 0.f), 127.f);
            float y0f = floorf(y), x0f = floorf(x);
            int y0 = (int)y0f, x0 = (int)x0f;
            int iy0 = y0 - ry0, ix0 = x0 - rx0;
            int iy1 = min(y0 + 1, 127) - ry0, ix1 = min(x0 + 1, 127) - rx0;
            float ly = y - y0f, lx = x - x0f;
            float hy = 1.f - ly, hx = 1.f - lx;
            const float sc = ok ? 1.f : 0.f;
            sum += sc * (reg[iy0 * 53 + ix0] * (hy * hx) + reg[iy0 * 53 + ix1] * (hy * lx)
                       + reg[iy1 * 53 + ix0] * (ly * hx) + reg[iy1 * 53 + ix1] * (ly * lx));
        }
        hb[pp] = __float2bfloat16(sum * 0.25f);
    }
}

// ========= K5b: roialign jobs 7-10 FUSED with rotation =====================
// Per block (n,c,jr): jr 0..3 = (xt1,b1),(xt1,b2),(xt2,b1),(xt2,b2).
// Phase 1: stage rotated-source bbox of f (<=60x60) into ft.
// Phase 2: compute xt pixels for the box region bit-identically to the old
//          gridsample (same fp32 exprs, tap order, validity-zero semantics).
// Phase 3: verified tap loop against the xt tile.
__device__ __forceinline__ float bt_tap(const float* ft, int sy0, int sx0,
                                        int nr, int nc2,
                                        float yy, float xx, float wt) {
    bool valid = (xx >= 0.f) & (xx < 128.f) & (yy >= 0.f) & (yy < 128.f);
    int xi = (int)fminf(fmaxf(xx, 0.f), 127.f);
    int yi = (int)fminf(fmaxf(yy, 0.f), 127.f);
    int r = min(max(yi - sy0, 0), nr - 1);
    int cc = min(max(xi - sx0, 0), nc2 - 1);
    return valid ? ft[r * 61 + cc] * wt : 0.f;
}

__global__ __launch_bounds__(256) void k_roialign_rot(const float* __restrict__ f,
                                                      const float* __restrict__ box,
                                                      __hip_bfloat16* __restrict__ h) {
    __shared__ float ft[60 * 61];       // rotated-source f tile
    __shared__ float xtt[52 * 53];      // xt box-region tile
    const int bx = blockIdx.x;          // 16n * 64c * 4 = 4096
    const int jr = bx & 3;
    const int nc = bx >> 2;
    const int c = nc & 63;
    const int n = nc >> 6;
    const float s5 = (jr >> 1) ? -S5 : S5;   // xt1: +S5, xt2: -S5
    const int j = jr & 1;
    const int cbase = 448 + jr * 64;
    const float* bp = box + n * 28 + j * 4;
    const float x1 = bp[0] * 0.25f, y1 = bp[1] * 0.25f;
    const float x2 = bp[2] * 0.25f, y2 = bp[3] * 0.25f;
    const float bw = fmaxf(x2 - x1, 1.f) * (1.f / 23.f);
    const float bh = fmaxf(y2 - y1, 1.f) * (1.f / 23.f);

    // xt-space region (identical to k_roialign_f)
    const int ry0 = (int)floorf(fminf(fmaxf(y1 + 0.25f * bh, 0.f), 127.f));
    int ry1 = min((int)floorf(fminf(fmaxf(y1 + 22.75f * bh, 0.f), 127.f)) + 1, 127);
    ry1 = min(ry1, ry0 + 51);
    const int rx0 = (int)floorf(fminf(fmaxf(x1 + 0.25f * bw, 0.f), 127.f));
    int rx1 = min((int)floorf(fminf(fmaxf(x1 + 22.75f * bw, 0.f), 127.f)) + 1, 127);
    rx1 = min(rx1, rx0 + 51);
    const int RH = ry1 - ry0 + 1, RW = rx1 - rx0 + 1;

    // rotated-source bbox from the 4 region corners (affine -> corner extremes),
    // +-1 margin for fp safety
    const float gxa = (2 * rx0 + 1) * (1.f / 128.f) - 1.f;
    const float gxb = (2 * rx1 + 1) * (1.f / 128.f) - 1.f;
    const float gya = (2 * ry0 + 1) * (1.f / 128.f) - 1.f;
    const float gyb = (2 * ry1 + 1) * (1.f / 128.f) - 1.f;
    float ixm = 1e30f, ixM = -1e30f, iym = 1e30f, iyM = -1e30f;
#pragma unroll
    for (int k = 0; k < 4; k++) {
        const float gx = (k & 1) ? gxb : gxa;
        const float gy = (k & 2) ? gyb : gya;
        const float g0 = C5 * gx + s5 * gy;
        const float g1 = -s5 * gx + C5 * gy;
        const float ix = ((g0 + 1.f) * 128.f - 1.f) * 0.5f;
        const float iy = ((g1 + 1.f) * 128.f - 1.f) * 0.5f;
        ixm = fminf(ixm, ix); ixM = fmaxf(ixM, ix);
        iym = fminf(iym, iy); iyM = fmaxf(iyM, iy);
    }
    const int sx0 = max(0, (int)floorf(fminf(fmaxf(ixm, 0.f), 127.f)) - 1);
    int sx1 = min(127, (int)floorf(fminf(fmaxf(ixM, 0.f), 127.f)) + 2);
    sx1 = min(sx1, sx0 + 59);
    const int sy0 = max(0, (int)floorf(fminf(fmaxf(iym, 0.f), 127.f)) - 1);
    int sy1 = min(127, (int)floorf(fminf(fmaxf(iyM, 0.f), 127.f)) + 2);
    sy1 = min(sy1, sy0 + 59);
    const int RH2 = sy1 - sy0 + 1, RW2 = sx1 - sx0 + 1;

    // ---- phase 1: stage f source tile ----
    const float* img = f + (size_t)(n * 64 + c) * 16384;
    const int tid = threadIdx.x;
    const int lane = tid & 63, wv = tid >> 6;
    for (int r = wv; r < RH2; r += 4)
        if (lane < RW2)
            ft[r * 61 + lane] = img[(sy0 + r) * 128 + sx0 + lane];
    __syncthreads();

    // ---- phase 2: compute xt pixels (bit-identical to old gridsample) ----
    for (int e = tid; e < RH * RW; e += 256) {
        const int r = e / RW, cw = e - r * RW;
        const int hh = ry0 + r, ww = rx0 + cw;
        const float gx = (2 * ww + 1) * (1.f / 128.f) - 1.f;
        const float gy = (2 * hh + 1) * (1.f / 128.f) - 1.f;
        const float g0 = C5 * gx + s5 * gy;
        const float g1 = -s5 * gx + C5 * gy;
        const float ix = ((g0 + 1.f) * 128.f - 1.f) * 0.5f;
        const float iy = ((g1 + 1.f) * 128.f - 1.f) * 0.5f;
        const float x0f = floorf(ix), y0f = floorf(iy);
        const float lx = ix - x0f, ly = iy - y0f;
        const float wa = (1.f - lx) * (1.f - ly);
        const float wb = (1.f - lx) * ly;
        const float wc = lx * (1.f - ly);
        const float wd = lx * ly;
        xtt[r * 53 + cw] = bt_tap(ft, sy0, sx0, RH2, RW2, y0f,       x0f,       wa)
                         + bt_tap(ft, sy0, sx0, RH2, RW2, y0f + 1.f, x0f,       wb)
                         + bt_tap(ft, sy0, sx0, RH2, RW2, y0f,       x0f + 1.f, wc)
                         + bt_tap(ft, sy0, sx0, RH2, RW2, y0f + 1.f, x0f + 1.f, wd);
    }
    __syncthreads();

    // ---- phase 3: verified tap loop on xt tile ----
    __hip_bfloat16* hb = h + (size_t)(n * 704 + cbase + c) * 529;
    for (int pp = tid; pp < 529; pp += 256) {
        const int ph = pp / 23, pw = pp - ph * 23;
        float sum = 0.f;
#pragma unroll
        for (int s = 0; s < 4; s++) {
            const int r1 = s >> 1, r2 = s & 1;
            const float yv = y1 + (ph + r1 * 0.5f + 0.25f) * bh;
            const float xv = x1 + (pw + r2 * 0.5f + 0.25f) * bw;
            const bool ok = !(yv < -1.f || yv > 128.f || xv < -1.f || xv > 128.f);
            float y = fminf(fmaxf(yv, 0.f), 127.f);
            float x = fminf(fmaxf(xv, 0.f), 127.f);
            float y0f = floorf(y), x0f = floorf(x);
            int y0 = (int)y0f, x0 = (int)x0f;
            int iy0 = y0 - ry0, ix0 = x0 - rx0;
            int iy1 = min(y0 + 1, 127) - ry0, ix1 = min(x0 + 1, 127) - rx0;
            float ly = y - y0f, lx = x - x0f;
            float hy = 1.f - ly, hx = 1.f - lx;
            const float sc = ok ? 1.f : 0.f;
            sum += sc * (xtt[iy0 * 53 + ix0] * (hy * hx) + xtt[iy0 * 53 + ix1] * (hy * lx)
                       + xtt[iy1 * 53 + ix0] * (ly * hx) + xtt[iy1 * 53 + ix1] * (ly * lx));
        }
        hb[pp] = __float2bfloat16(sum * 0.25f);
    }
}

// ========= K6: conv1 MFMA bf16, split-K=9, double-buffered staging =========
__global__ __launch_bounds__(256) void k_conv1m(const ushort* __restrict__ hb,
                                                const ushort* __restrict__ w1b,
                                                float* __restrict__ c1p) {
    __shared__ __align__(16) ushort Bs[2][2][32][40];  // [buf][panel][pos][kk]
    const int bx = blockIdx.x;
    const int pt = bx % 17;
    const int n  = (bx / 17) & 15;
    const int s  = bx / 272;
    const int tid = threadIdx.x;
    const int w = tid >> 6, lane = tid & 63;
    const int quad = lane >> 4, m = lane & 15;
    const int kbase = s * 704;
    const int posb = pt * 32;
    const size_t hb_n = (size_t)n * 704 * 529;
    f32x4 acc0 = {0.f, 0.f, 0.f, 0.f};
    f32x4 acc1 = {0.f, 0.f, 0.f, 0.f};
    const ushort* wrow = w1b + (size_t)(w * 16 + m) * 6336;

    int ep[8], ek[8], epos[8];
#pragma unroll
    for (int i = 0; i < 8; i++) {
        const int e = tid + 256 * i;
        ep[i] = e >> 10; ek[i] = (e >> 5) & 31; epos[i] = e & 31;
    }
    ushort rbuf[8];
#pragma unroll
    for (int i = 0; i < 8; i++) {          // preload it=0
        const int k = kbase + ep[i] * 32 + ek[i];
        const int ci = k / 9, tap = k - ci * 9;
        const int kh = tap / 3, kw = tap - kh * 3;
        rbuf[i] = hb[hb_n + (size_t)ci * 529 + kh * 23 + kw + posb + epos[i]];
    }
#pragma unroll
    for (int i = 0; i < 8; i++) Bs[0][ep[i]][epos[i]][ek[i]] = rbuf[i];

    for (int it = 0; it < 11; it++) {
        __syncthreads();                    // Bs[it&1] ready
        const int cur = it & 1;
        if (it < 10) {
            const int k0 = kbase + (it + 1) * 64;
#pragma unroll
            for (int i = 0; i < 8; i++) {
                const int k = k0 + ep[i] * 32 + ek[i];
                const int ci = k / 9, tap = k - ci * 9;
                const int kh = tap / 3, kw = tap - kh * 3;
                rbuf[i] = hb[hb_n + (size_t)ci * 529 + kh * 23 + kw + posb + epos[i]];
            }
        }
        const int k0 = kbase + it * 64;
        const short8 a0  = *(const short8*)(wrow + k0 + quad * 8);
        const short8 a1  = *(const short8*)(wrow + k0 + 32 + quad * 8);
        const short8 b00 = *(const short8*)&Bs[cur][0][m][quad * 8];
        const short8 b01 = *(const short8*)&Bs[cur][0][16 + m][quad * 8];
        const short8 b10 = *(const short8*)&Bs[cur][1][m][quad * 8];
        const short8 b11 = *(const short8*)&Bs[cur][1][16 + m][quad * 8];
        acc0 = __builtin_amdgcn_mfma_f32_16x16x32_bf16(a0, b00, acc0, 0, 0, 0);
        acc1 = __builtin_amdgcn_mfma_f32_16x16x32_bf16(a0, b01, acc1, 0, 0, 0);
        acc0 = __builtin_amdgcn_mfma_f32_16x16x32_bf16(a1, b10, acc0, 0, 0, 0);
        acc1 = __builtin_amdgcn_mfma_f32_16x16x32_bf16(a1, b11, acc1, 0, 0, 0);
        if (it < 10) {
#pragma unroll
            for (int i = 0; i < 8; i++) Bs[cur ^ 1][ep[i]][epos[i]][ek[i]] = rbuf[i];
        }
    }
    float* outp = c1p + ((size_t)(s * 16 + n) * 64) * 544;
#pragma unroll
    for (int r = 0; r < 4; r++) {
        const int oc = w * 16 + quad * 4 + r;
        outp[(size_t)oc * 544 + posb + m]      = acc0[r];
        outp[(size_t)oc * 544 + posb + 16 + m] = acc1[r];
    }
}

// =================== K6b: split-K(9) reduce + bias =========================
__global__ __launch_bounds__(256) void k_c1red(const float* __restrict__ c1p,
                                               const float* __restrict__ b1,
                                               float* __restrict__ c1) {
    const int t = blockIdx.x * 256 + threadIdx.x;   // 451584 exact
    const int p = t % 441;
    const int oc = (t / 441) % 64;
    const int n = t / 28224;
    const int ph = p / 21, pw = p - ph * 21;
    const int p529 = ph * 23 + pw;
    const size_t base = ((size_t)n * 64 + oc) * 544 + p529;
    const size_t sstr = (size_t)16 * 64 * 544;
    float v = 0.f;
#pragma unroll
    for (int k = 0; k < 9; k++) v += c1p[base + k * sstr];
    c1[t] = v + b1[oc];
}

// ================ K8: BN1 apply + relu + maxpool 2x2/s2 ====================
__global__ __launch_bounds__(256) void k_bnpool2(const float* __restrict__ c1,
                                                 const float* __restrict__ stats1,
                                                 float* __restrict__ p1) {
    const int t = blockIdx.x * 256 + threadIdx.x;   // 102400 exact
    const int pw = t % 10;
    const int ph = (t / 10) % 10;
    const int c = (t / 100) % 64;
    const int n = t / 6400;
    const float a = stats1[c], b = stats1[64 + c];
    const float* base = c1 + (size_t)(n * 64 + c) * 441;
    const int r = ph * 2, cc = pw * 2;
    float v0 = a * base[r * 21 + cc] + b;
    float v1 = a * base[r * 21 + cc + 1] + b;
    float v2 = a * base[(r + 1) * 21 + cc] + b;
    float v3 = a * base[(r + 1) * 21 + cc + 1] + b;
    p1[t] = fmaxf(fmaxf(fmaxf(v0, v1), fmaxf(v2, v3)), 0.f);
}

// ========== K9: conv2 3x3 (64->32) + bias + relu, LDS-staged ===============
__global__ __launch_bounds__(256) void k_conv2(const float* __restrict__ p1,
                                               const float* __restrict__ w2,
                                               const float* __restrict__ b2,
                                               float* __restrict__ c2) {
    __shared__ float ip[6400];      // 64 ci x 100
    __shared__ float wl[2304];      // 4 oc x 576
    const int bx = blockIdx.x;
    const int n = bx >> 3, ocq = bx & 7;
    const int tid = threadIdx.x;
    const float4* p14 = (const float4*)(p1 + (size_t)n * 6400);
    float4* ip4 = (float4*)ip;
    for (int e = tid; e < 1600; e += 256) ip4[e] = p14[e];
    for (int e = tid; e < 2304; e += 256) wl[e] = w2[ocq * 2304 + e];
    __syncthreads();

    const int ocl = tid >> 6, pos = tid & 63;
    const int ph = pos >> 3, pw = pos & 7;
    const int oc = ocq * 4 + ocl;
    float s = b2[oc];
    const float* wb = wl + ocl * 576;
    const float* ib = ip + ph * 10 + pw;
    for (int ci = 0; ci < 64; ci++) {
        const float* r = ib + ci * 100;
        const float* ww = wb + ci * 9;
        s += r[0] * ww[0] + r[1] * ww[1] + r[2] * ww[2]
           + r[10] * ww[3] + r[11] * ww[4] + r[12] * ww[5]
           + r[20] * ww[6] + r[21] * ww[7] + r[22] * ww[8];
    }
    c2[(size_t)(n * 32 + oc) * 64 + pos] = fmaxf(s, 0.f);
}

// ======================= K10: fc1 + relu ===================================
__global__ __launch_bounds__(64) void k_fc1(const float* __restrict__ c2,
                                            const float* __restrict__ fw,
                                            const float* __restrict__ fb,
                                            float* __restrict__ fo) {
    const int bx = blockIdx.x;
    const int oc = bx & 127, n = bx >> 7;
    const int lane = threadIdx.x;
    const float* a = c2 + (size_t)n * 2048;
    const float* w = fw + (size_t)oc * 2048;
    float s = 0.f;
    for (int k = lane; k < 2048; k += 64) s += a[k] * w[k];
#pragma unroll
    for (int off = 32; off; off >>= 1) s += __shfl_xor(s, off, 64);
    if (lane == 0) fo[n * 128 + oc] = fmaxf(s + fb[oc], 0.f);
}

// ======================= K11: head + tanh ==================================
__global__ __launch_bounds__(64) void k_head(const float* __restrict__ fo,
                                             const float* __restrict__ hw,
                                             const float* __restrict__ hb,
                                             float* __restrict__ out) {
    const int bx = blockIdx.x;
    const int oc = bx % 12, n = bx / 12;
    const int lane = threadIdx.x;
    float s = 0.f;
    for (int k = lane; k < 128; k += 64) s += fo[n * 128 + k] * hw[oc * 128 + k];
#pragma unroll
    for (int off = 32; off; off >>= 1) s += __shfl_xor(s, off, 64);
    if (lane == 0) out[bx] = tanhf(s + hb[oc]);
}

// ===========================================================================
extern "C" void kernel_launch(void* const* d_in, const int* in_sizes, int n_in,
                              void* d_out, int out_size, void* d_ws, size_t ws_size,
                              hipStream_t stream) {
    const float* x       = (const float*)d_in[0];
    const float* box     = (const float*)d_in[1];
    const float* stem_w  = (const float*)d_in[2];
    const float* stem_g  = (const float*)d_in[3];
    const float* stem_b  = (const float*)d_in[4];
    const float* conv1_w = (const float*)d_in[5];
    const float* conv1_b = (const float*)d_in[6];
    const float* bn1_g   = (const float*)d_in[7];
    const float* bn1_b   = (const float*)d_in[8];
    const float* conv2_w = (const float*)d_in[9];
    const float* conv2_b = (const float*)d_in[10];
    const float* fc1_w   = (const float*)d_in[11];
    const float* fc1_b   = (const float*)d_in[12];
    const float* head_w  = (const float*)d_in[13];
    const float* head_b  = (const float*)d_in[14];
    float* out = (float*)d_out;
    float* w = (float*)d_ws;

    const size_t F_SZ = 16777216;                         // 16*64*128*128
    float* f   = w;                                       // fp32
    ushort* xbf = (ushort*)w;                             // aliases f (dead before k_bnpool)
    float* c1p = w;                                       // aliases f (dead after roialign)
                                                          // 9*16*64*544 = 5013504 < F_SZ
    __hip_bfloat16* stem = (__hip_bfloat16*)(w + F_SZ);   // bf16, spans 2*F_SZ floats
    float* base3 = w + 3 * F_SZ;
    __hip_bfloat16* hbuf = (__hip_bfloat16*)base3;        // 5958656 els = 2979328+pad
    float* c1   = base3 + 2979392;                        // 451584
    float* p1   = c1 + 451584;                            // 102400
    float* c2   = p1 + 102400;                            // 32768
    float* fo   = c2 + 32768;                             // 2048
    float* stats_raw = fo + 2048;                         // 128 (S,Q interleaved)
    float* stats1  = stats_raw + 128;                     // 128
    __hip_bfloat16* w1b = (__hip_bfloat16*)(stats1 + 128); // 405504 els
    __hip_bfloat16* w2b = (__hip_bfloat16*)(stats1 + 128 + 202752); // 12288 els

    k_cvtall<<<14263, 256, 0, stream>>>(x, xbf, conv1_w, w1b, stem_w, w2b, stats_raw);
    k_stem<<<16384, 64, 0, stream>>>(xbf, (const ushort*)w2b, stem);
    k_sumstem<<<512, 256, 0, stream>>>((const ushort*)stem, stats_raw);
    k_bnpool<<<8192, 256, 0, stream>>>(stem, stats_raw, stem_g, stem_b, f);
    k_roialign_f<<<7168, 256, 0, stream>>>(f, box, hbuf);
    k_roialign_rot<<<4096, 256, 0, stream>>>(f, box, hbuf);
    k_conv1m<<<2448, 256, 0, stream>>>((const ushort*)hbuf, (const ushort*)w1b, c1p);
    k_c1red<<<1764, 256, 0, stream>>>(c1p, conv1_b, c1);
    k_bn1stats<<<64, 256, 0, stream>>>(c1, bn1_g, bn1_b, stats1);
    k_bnpool2<<<400, 256, 0, stream>>>(c1, stats1, p1);
    k_conv2<<<128, 256, 0, stream>>>(p1, conv2_w, conv2_b, c2);
    k_fc1<<<2048, 64, 0, stream>>>(c2, fc1_w, fc1_b, fo);
    k_head<<<192, 64, 0, stream>>>(fo, head_w, head_b, out);
}